// Round 1
// 525.969 us; speedup vs baseline: 1.0157x; 1.0157x over previous
//
#include <hip/hip_runtime.h>

typedef unsigned int uint32;
typedef _Float16 f16;
typedef _Float16 f16x8 __attribute__((ext_vector_type(8)));
typedef float f32x4 __attribute__((ext_vector_type(4)));

#define B_SZ 4
#define T_SZ 4096
#define DMODEL 512
#define NHEAD 8
#define DH 64
#define NHASH 4
#define BH (B_SZ*NHEAD)      // 32
#define NBUCK 256
#define TOT (NHASH*T_SZ)     // 16384
#define M_TOK (B_SZ*T_SZ)    // 16384

#define KSTRIDE 72           // f16 elems per LDS row (128B data + 16B pad)
#define PSTRIDE 136

// split-f16 MFMA hash-score worst-case error ~4e-5*rms; keep >=35x margin.
#define AMB_TAU 1.5e-3f

// ---------------- K0: zero histogram + ambiguity counter ----------------
__global__ void k0_zero(int* hist, int* amb_cnt){
  hist[blockIdx.x*256 + threadIdx.x] = 0;
  if (blockIdx.x == 0 && threadIdx.x == 0) *amb_cnt = 0;
}

// ---------------- KW: transpose + split W matrices into Wt[n][k] f16 hi/lo ----
__global__ __launch_bounds__(256) void kw_t(const float* __restrict__ Wqk,
    const float* __restrict__ Wv, const float* __restrict__ Wout,
    f16* __restrict__ Wth, f16* __restrict__ Wtl)
{
  int gid = blockIdx.x*256 + threadIdx.x;   // [0, 1536*512)
  int n = gid >> 9, k = gid & 511;
  int sel = n >> 9, col = n & 511;
  const float* src = (sel==0)? Wqk : (sel==1)? Wv : Wout;
  float v = src[(size_t)k*512 + col];
  f16 h = (f16)v;
  Wth[gid] = h;
  Wtl[gid] = (f16)(v - (float)h);
}

// ---------------- KR: transpose + split rotations into rotT[n=h*32+j][k=dd] --
__global__ __launch_bounds__(256) void kr_t(const float* __restrict__ rot,
    f16* __restrict__ rotTh, f16* __restrict__ rotTl)
{
  int gid = blockIdx.x*256 + threadIdx.x;   // [0, 128*64)
  int n = gid >> 6, dd = gid & 63;
  float v = rot[dd*128 + n];
  f16 h = (f16)v;
  rotTh[gid] = h;
  rotTl[gid] = (f16)(v - (float)h);
}

// ---------------- K1a: split queries (f32) -> A_hi/A_lo (f16) ----------------
__global__ __launch_bounds__(256) void k1a_split(const float* __restrict__ qin,
    f16* __restrict__ Ah, f16* __restrict__ Al)
{
  size_t gid = (size_t)blockIdx.x*256 + threadIdx.x;   // handles 8 floats
  const float4* src = (const float4*)(qin) + gid*2;
  float4 x0 = src[0], x1 = src[1];
  float v[8] = {x0.x,x0.y,x0.z,x0.w, x1.x,x1.y,x1.z,x1.w};
  f16x8 h, l;
  #pragma unroll
  for (int e=0;e<8;e++){ f16 hh=(f16)v[e]; h[e]=hh; l[e]=(f16)(v[e]-(float)hh); }
  ((f16x8*)Ah)[gid] = h;
  ((f16x8*)Al)[gid] = l;
}

// ---------------- G1: split-f16 MFMA GEMM  qk|v = queries @ [Wqk|Wv] ---------
__global__ __launch_bounds__(256) void g_qkv(const f16* __restrict__ Ah,
    const f16* __restrict__ Al, const f16* __restrict__ Wth, const f16* __restrict__ Wtl,
    f16* __restrict__ qk16, f16* __restrict__ qkl, f16* __restrict__ v16)
{
  __shared__ f16 ah[128*KSTRIDE], al[128*KSTRIDE], bh[128*KSTRIDE], bl[128*KSTRIDE];
  int tid = threadIdx.x;
  int m0 = blockIdx.x*128, n0 = blockIdx.y*128;
  int w = tid >> 6, lane = tid & 63;
  int wm = w >> 1, wn = w & 1;
  int c_lane = lane & 15, quad = lane >> 4;

  f32x4 acc[4][4];
  #pragma unroll
  for (int mi=0;mi<4;mi++)
    #pragma unroll
    for (int ni=0;ni<4;ni++) acc[mi][ni] = (f32x4){0.f,0.f,0.f,0.f};

  int sr = tid >> 1, sc = (tid & 1) * 32;
  for (int kc=0; kc<8; kc++){
    int k0 = kc*64;
    {
      const f16x8* pah = (const f16x8*)(Ah + (size_t)(m0+sr)*512 + k0 + sc);
      const f16x8* pal = (const f16x8*)(Al + (size_t)(m0+sr)*512 + k0 + sc);
      const f16x8* pbh = (const f16x8*)(Wth + (size_t)(n0+sr)*512 + k0 + sc);
      const f16x8* pbl = (const f16x8*)(Wtl + (size_t)(n0+sr)*512 + k0 + sc);
      f16x8* dah = (f16x8*)&ah[sr*KSTRIDE + sc];
      f16x8* dal = (f16x8*)&al[sr*KSTRIDE + sc];
      f16x8* dbh = (f16x8*)&bh[sr*KSTRIDE + sc];
      f16x8* dbl = (f16x8*)&bl[sr*KSTRIDE + sc];
      #pragma unroll
      for (int i=0;i<4;i++){ dah[i]=pah[i]; dal[i]=pal[i]; dbh[i]=pbh[i]; dbl[i]=pbl[i]; }
    }
    __syncthreads();
    f16x8 fah[4][2], fal[4][2], fbh[4][2], fbl[4][2];
    #pragma unroll
    for (int i=0;i<4;i++)
      #pragma unroll
      for (int kb=0;kb<2;kb++){
        int ma = (wm*64 + i*16 + c_lane)*KSTRIDE + kb*32 + quad*8;
        int nb = (wn*64 + i*16 + c_lane)*KSTRIDE + kb*32 + quad*8;
        fah[i][kb] = *(const f16x8*)&ah[ma];
        fal[i][kb] = *(const f16x8*)&al[ma];
        fbh[i][kb] = *(const f16x8*)&bh[nb];
        fbl[i][kb] = *(const f16x8*)&bl[nb];
      }
    #pragma unroll
    for (int kb=0;kb<2;kb++)
      #pragma unroll
      for (int p=0;p<3;p++)
        #pragma unroll
        for (int mi=0;mi<4;mi++)
          #pragma unroll
          for (int ni=0;ni<4;ni++){
            f16x8 a = (p==2)? fal[mi][kb] : fah[mi][kb];
            f16x8 b = (p==1)? fbl[ni][kb] : fbh[ni][kb];
            acc[mi][ni] = __builtin_amdgcn_mfma_f32_16x16x32_f16(a, b, acc[mi][ni], 0,0,0);
          }
    __syncthreads();
  }

  // epilogue: n<512 -> qk16(hi)+qkl(lo); n>=512 -> v16
  #pragma unroll
  for (int mi=0;mi<4;mi++)
    #pragma unroll
    for (int ni=0;ni<4;ni++)
      #pragma unroll
      for (int r=0;r<4;r++){
        int n = n0 + wn*64 + ni*16 + c_lane;
        int tok = m0 + wm*64 + mi*16 + quad*4 + r;
        float val = acc[mi][ni][r];
        int b = tok >> 12, tp = tok & 4095;
        if (n < 512){
          int head = n >> 6, dd = n & 63;
          size_t idx = ((size_t)(b*NHEAD+head)*T_SZ + tp)*DH + dd;
          f16 hv = (f16)val;
          qk16[idx] = hv;
          qkl[idx]  = (f16)(val - (float)hv);
        } else {
          int j = n - 512, head = j >> 6, dd = j & 63;
          size_t idx = ((size_t)(b*NHEAD+head)*T_SZ + tp)*DH + dd;
          v16[idx] = (f16)val;
        }
      }
}

// ---------------- G2: split-f16 MFMA GEMM  out = X @ Wout + bias -------------
__global__ __launch_bounds__(256) void g_out(const f16* __restrict__ Xh,
    const f16* __restrict__ Xl, const f16* __restrict__ Wth, const f16* __restrict__ Wtl,
    const float* __restrict__ bout, float* __restrict__ out)
{
  __shared__ f16 ah[128*KSTRIDE], al[128*KSTRIDE], bh[128*KSTRIDE], bl[128*KSTRIDE];
  int tid = threadIdx.x;
  int m0 = blockIdx.x*128, n0 = blockIdx.y*128;
  int w = tid >> 6, lane = tid & 63;
  int wm = w >> 1, wn = w & 1;
  int c_lane = lane & 15, quad = lane >> 4;
  const f16* Bh_base = Wth + (size_t)1024*512;   // Wout section
  const f16* Bl_base = Wtl + (size_t)1024*512;

  f32x4 acc[4][4];
  #pragma unroll
  for (int mi=0;mi<4;mi++)
    #pragma unroll
    for (int ni=0;ni<4;ni++) acc[mi][ni] = (f32x4){0.f,0.f,0.f,0.f};

  int sr = tid >> 1, sc = (tid & 1) * 32;
  for (int kc=0; kc<8; kc++){
    int k0 = kc*64;
    {
      const f16x8* pah = (const f16x8*)(Xh + (size_t)(m0+sr)*512 + k0 + sc);
      const f16x8* pal = (const f16x8*)(Xl + (size_t)(m0+sr)*512 + k0 + sc);
      const f16x8* pbh = (const f16x8*)(Bh_base + (size_t)(n0+sr)*512 + k0 + sc);
      const f16x8* pbl = (const f16x8*)(Bl_base + (size_t)(n0+sr)*512 + k0 + sc);
      f16x8* dah = (f16x8*)&ah[sr*KSTRIDE + sc];
      f16x8* dal = (f16x8*)&al[sr*KSTRIDE + sc];
      f16x8* dbh = (f16x8*)&bh[sr*KSTRIDE + sc];
      f16x8* dbl = (f16x8*)&bl[sr*KSTRIDE + sc];
      #pragma unroll
      for (int i=0;i<4;i++){ dah[i]=pah[i]; dal[i]=pal[i]; dbh[i]=pbh[i]; dbl[i]=pbl[i]; }
    }
    __syncthreads();
    f16x8 fah[4][2], fal[4][2], fbh[4][2], fbl[4][2];
    #pragma unroll
    for (int i=0;i<4;i++)
      #pragma unroll
      for (int kb=0;kb<2;kb++){
        int ma = (wm*64 + i*16 + c_lane)*KSTRIDE + kb*32 + quad*8;
        int nb = (wn*64 + i*16 + c_lane)*KSTRIDE + kb*32 + quad*8;
        fah[i][kb] = *(const f16x8*)&ah[ma];
        fal[i][kb] = *(const f16x8*)&al[ma];
        fbh[i][kb] = *(const f16x8*)&bh[nb];
        fbl[i][kb] = *(const f16x8*)&bl[nb];
      }
    #pragma unroll
    for (int kb=0;kb<2;kb++)
      #pragma unroll
      for (int p=0;p<3;p++)
        #pragma unroll
        for (int mi=0;mi<4;mi++)
          #pragma unroll
          for (int ni=0;ni<4;ni++){
            f16x8 a = (p==2)? fal[mi][kb] : fah[mi][kb];
            f16x8 b = (p==1)? fbl[ni][kb] : fbh[ni][kb];
            acc[mi][ni] = __builtin_amdgcn_mfma_f32_16x16x32_f16(a, b, acc[mi][ni], 0,0,0);
          }
    __syncthreads();
  }

  #pragma unroll
  for (int mi=0;mi<4;mi++)
    #pragma unroll
    for (int ni=0;ni<4;ni++){
      int n = n0 + wn*64 + ni*16 + c_lane;
      float bn = bout[n];
      #pragma unroll
      for (int r=0;r<4;r++){
        int tok = m0 + wm*64 + mi*16 + quad*4 + r;
        out[(size_t)tok*512 + n] = acc[mi][ni][r] + bn;
      }
    }
}

// ---------------- K2: LSH hashing as split-f16 MFMA GEMM + argmax epilogue ----
__global__ __launch_bounds__(256) void k2_mfma(const f16* __restrict__ qkh,
    const f16* __restrict__ qkl, const f16* __restrict__ rotTh, const f16* __restrict__ rotTl,
    unsigned short* __restrict__ bucket, int* __restrict__ hist,
    int* __restrict__ amb_list, int* __restrict__ amb_cnt)
{
  int tid = threadIdx.x;
  int w = tid >> 6, lane = tid & 63;
  int wm = w >> 1, wn = w & 1;
  int c_lane = lane & 15, quad = lane >> 4;
  size_t m0 = (size_t)blockIdx.x*128 + wm*64;

  f16x8 fbh[4][2], fbl[4][2];
  #pragma unroll
  for (int ni=0;ni<4;ni++)
    #pragma unroll
    for (int kb=0;kb<2;kb++){
      int n = wn*64 + ni*16 + c_lane;
      fbh[ni][kb] = *(const f16x8*)&rotTh[n*64 + kb*32 + quad*8];
      fbl[ni][kb] = *(const f16x8*)&rotTl[n*64 + kb*32 + quad*8];
    }

  f32x4 acc[4][4];
  #pragma unroll
  for (int mi=0;mi<4;mi++)
    #pragma unroll
    for (int ni=0;ni<4;ni++) acc[mi][ni] = (f32x4){0.f,0.f,0.f,0.f};

  #pragma unroll
  for (int mi=0;mi<4;mi++){
    size_t row = m0 + mi*16 + c_lane;
    f16x8 fah[2], fal[2];
    #pragma unroll
    for (int kb=0;kb<2;kb++){
      fah[kb] = *(const f16x8*)&qkh[row*64 + kb*32 + quad*8];
      fal[kb] = *(const f16x8*)&qkl[row*64 + kb*32 + quad*8];
    }
    #pragma unroll
    for (int kb=0;kb<2;kb++)
      #pragma unroll
      for (int ni=0;ni<4;ni++){
        acc[mi][ni] = __builtin_amdgcn_mfma_f32_16x16x32_f16(fah[kb], fbh[ni][kb], acc[mi][ni], 0,0,0);
        acc[mi][ni] = __builtin_amdgcn_mfma_f32_16x16x32_f16(fah[kb], fbl[ni][kb], acc[mi][ni], 0,0,0);
        acc[mi][ni] = __builtin_amdgcn_mfma_f32_16x16x32_f16(fal[kb], fbh[ni][kb], acc[mi][ni], 0,0,0);
      }
  }

  #pragma unroll
  for (int mi=0;mi<4;mi++){
    #pragma unroll
    for (int r=0;r<4;r++){
      int tok = (int)m0 + mi*16 + quad*4 + r;
      int bhh = tok >> 12, t = tok & 4095;
      #pragma unroll
      for (int hl=0; hl<2; hl++){
        int h = wn*2 + hl;
        float v0 = acc[mi][2*hl][r];     // col j = c_lane
        float v1 = acc[mi][2*hl+1][r];   // col j = 16 + c_lane
        float m1 = v0, m2 = -1e30f; int b1 = c_lane;
        if (v1 > m1){ m2 = m1; m1 = v1; b1 = 16 + c_lane; } else m2 = v1;
        float n0v = -v0, n1v = -v1;
        if (n0v > m1){ m2 = m1; m1 = n0v; b1 = 32 + c_lane; } else if (n0v > m2) m2 = n0v;
        if (n1v > m1){ m2 = m1; m1 = n1v; b1 = 48 + c_lane; } else if (n1v > m2) m2 = n1v;
        float ssq = v0*v0 + v1*v1;
        #pragma unroll
        for (int d2=1; d2<16; d2<<=1){
          float om1 = __shfl_xor(m1, d2);
          float om2 = __shfl_xor(m2, d2);
          int   ob1 = __shfl_xor(b1, d2);
          ssq += __shfl_xor(ssq, d2);
          if (om1 > m1){ m2 = fmaxf(m1, om2); m1 = om1; b1 = ob1; }
          else         { m2 = fmaxf(m2, om1); }
        }
        if (c_lane == 0){
          float rms = sqrtf(ssq * (1.0f/32.0f));
          if (m1 - m2 < AMB_TAU * rms){
            int idx = atomicAdd(amb_cnt, 1);
            amb_list[idx] = (bhh<<14) | (h<<12) | t;
          } else {
            int g = b1 + (h<<6);
            bucket[((bhh*NHASH + h)<<12) + t] = (unsigned short)g;
            atomicAdd(&hist[bhh*NBUCK + g], 1);
          }
        }
      }
    }
  }
}

// ---------------- K2fix: exact f64 recompute for ambiguous decisions ----------
__global__ __launch_bounds__(64) void k2_fix(const float* __restrict__ qin,
    const float* __restrict__ Wqk, const float* __restrict__ rot,
    const int* __restrict__ amb_list, const int* __restrict__ amb_cnt,
    unsigned short* __restrict__ bucket, int* __restrict__ hist)
{
  __shared__ __align__(16) float qs[512];
  __shared__ double qk64[64];
  __shared__ double accs[32];
  int n = *amb_cnt;
  int lane = threadIdx.x;
  for (int it = blockIdx.x; it < n; it += gridDim.x){
    int gid = amb_list[it];
    int t = gid & (T_SZ-1);
    int h = (gid >> 12) & 3;
    int bh = gid >> 14;
    int b = bh >> 3, head = bh & 7;
    const float4* qrow4 = (const float4*)(qin + ((size_t)b*T_SZ + t)*DMODEL);
    float4 x0 = qrow4[lane];
    float4 x1 = qrow4[lane + 64];
    *(float4*)&qs[lane*4]       = x0;
    *(float4*)&qs[256 + lane*4] = x1;
    __syncthreads();
    const float* wcol = Wqk + head*64 + lane;
    double s = 0.0;
    #pragma unroll 16
    for (int d=0; d<512; d++)
      s += (double)qs[d] * (double)wcol[(size_t)d*512];
    qk64[lane] = s;
    __syncthreads();
    if (lane < 32){
      double a = 0.0;
      #pragma unroll 16
      for (int f=0; f<64; f++)
        a += qk64[f] * (double)rot[f*(NHASH*32) + h*32 + lane];
      accs[lane] = a;
    }
    __syncthreads();
    if (lane == 0){
      double best = accs[0]; int bk = 0;
      for (int k=1;k<64;k++){
        double vv = (k<32)? accs[k] : -accs[k-32];
        if (vv > best){ best = vv; bk = k; }
      }
      int g = bk + (h<<6);
      bucket[((bh*NHASH + h)<<12) + t] = (unsigned short)g;
      atomicAdd(&hist[bh*NBUCK + g], 1);
    }
    __syncthreads();
  }
}

// ---------------- K3: per-bh exclusive prefix over 256 buckets ----------------
__global__ __launch_bounds__(256) void k3_scan(const int* __restrict__ hist, int* __restrict__ starts){
  __shared__ int s[256];
  int bh = blockIdx.x, tid = threadIdx.x;
  int v = hist[bh*256 + tid];
  s[tid] = v; __syncthreads();
  for (int off=1; off<256; off<<=1){
    int a = (tid >= off) ? s[tid-off] : 0;
    __syncthreads();
    s[tid] += a;
    __syncthreads();
  }
  starts[bh*256 + tid] = s[tid] - v;
}

// ---------------- K3b: stable counting-sort scatter ----------------
__global__ __launch_bounds__(64) void k3b_scatter(const unsigned short* __restrict__ bucket,
    const int* __restrict__ starts, int* __restrict__ st)
{
  int blk = blockIdx.x;
  int bh = blk >> 8; int g = blk & 255; int h = g >> 6;
  int lane = threadIdx.x;
  const unsigned short* brow = bucket + ((bh*NHASH + h)<<12);
  int base = starts[bh*NBUCK + g];
  for (int step=0; step<64; step++){
    int t = step*64 + lane;
    bool pred = (brow[t] == (unsigned short)g);
    unsigned long long mask = __ballot(pred);
    if (pred){
      int off = __popcll(mask & ((1ull<<lane) - 1ull));
      st[bh*TOT + base + off] = t;
    }
    base += __popcll(mask);
  }
}

// ---------------- K4: MFMA chunked LSH attention ------------------------------
// v2: 4 cooperative waves per chunk (wave w owns query sub-tile mi=w).
// Same LDS footprint (36864B -> 4 blocks/CU), but 256 threads/block:
// 16 waves/CU instead of 4. accS shrinks 128->32 VGPRs/wave so
// __launch_bounds__(256,4) holds without spill. XCD-aware swizzle keeps each
// XCD on 4 bh values (4MB gathered K/V working set == one L2).
// Accumulation order per (mi,ni,r) is bit-identical to v1.
__global__ __launch_bounds__(256, 4) void k4_attn(const f16* __restrict__ qk16,
    const f16* __restrict__ v16, const int* __restrict__ st,
    float* __restrict__ lse_out, f16* __restrict__ o_out)
{
  __shared__ __align__(16) char smem[36864];
  f16*   k_lds   = (f16*)smem;                 // 128 x KSTRIDE (alias p_lds)
  f16*   p_lds   = (f16*)smem;                 // 64 x PSTRIDE
  f16*   vT      = (f16*)(smem + 18432);       // 64 x PSTRIDE (d-major)
  float* invnorm = (float*)(smem + 35840);
  int*   kv_t    = (int*)(smem + 36352);

  int bid = blockIdx.x;
  int swz = (bid & 7) * 1024 + (bid >> 3);     // bijective: 8192 = 8*1024
  int bh = swz >> 8; int c = swz & 255;
  int h = c >> 6; int cp = (c + 255) & 255;
  int tid = threadIdx.x;
  int w = tid >> 6, lane = tid & 63;
  int c_lane = lane & 15, quad = lane >> 4;
  const int* strow = st + bh*TOT;

  // ---- load phase: threads 0..127, one full K/V row each (conflict-free vT scatter)
  if (tid < 128){
    int row = tid;
    int slot = (row < 64) ? (c*64 + row) : (cp*64 + row - 64);
    int t = strow[slot];
    kv_t[row] = t;
    const f16x8* kr = (const f16x8*)(qk16 + ((size_t)bh*T_SZ + t)*DH);
    const f16x8* vr = (const f16x8*)(v16  + ((size_t)bh*T_SZ + t)*DH);
    f16x8 kv[8], vv[8];
    float ss = 0.f;
    #pragma unroll
    for (int i=0;i<8;i++){
      f16x8 x = kr[i]; kv[i] = x;
      vv[i] = vr[i];
      #pragma unroll
      for (int e=0;e<8;e++){ float f = (float)x[e]; ss += f*f; }
    }
    invnorm[row] = 1.0f / fmaxf(sqrtf(ss), 1e-12f);
    f16x8* kd = (f16x8*)&k_lds[row*KSTRIDE];
    #pragma unroll
    for (int i=0;i<8;i++) kd[i] = kv[i];
    #pragma unroll
    for (int i=0;i<8;i++){
      #pragma unroll
      for (int e=0;e<8;e++) vT[(i*8+e)*PSTRIDE + row] = vv[i][e];
    }
  }
  __syncthreads();

  // ---- QK^T: wave w computes query sub-tile mi = w ----
  int mi = w;
  f16x8 aq[2];
  #pragma unroll
  for (int kb=0;kb<2;kb++)
    aq[kb] = *(const f16x8*)&k_lds[(mi*16 + c_lane)*KSTRIDE + kb*32 + quad*8];

  f32x4 accS[8];
  #pragma unroll
  for (int ni=0;ni<8;ni++) accS[ni] = (f32x4){0.f,0.f,0.f,0.f};

  #pragma unroll
  for (int ni=0;ni<8;ni++){
    int rowb = ni*16 + c_lane;
    f16 sc = (f16)invnorm[rowb];
    f16x8 b0 = *(const f16x8*)&k_lds[rowb*KSTRIDE + 0*32 + quad*8];
    f16x8 b1 = *(const f16x8*)&k_lds[rowb*KSTRIDE + 1*32 + quad*8];
    b0 *= sc; b1 *= sc;
    accS[ni] = __builtin_amdgcn_mfma_f32_16x16x32_f16(aq[0], b0, accS[ni], 0,0,0);
    accS[ni] = __builtin_amdgcn_mfma_f32_16x16x32_f16(aq[1], b1, accS[ni], 0,0,0);
  }

  int tq[4];
  #pragma unroll
  for (int r=0;r<4;r++) tq[r] = kv_t[mi*16 + quad*4 + r];
  int tk[8];
  #pragma unroll
  for (int ni=0;ni<8;ni++) tk[ni] = kv_t[ni*16 + c_lane];

  float mrow[4], lrow[4];
  #pragma unroll
  for (int r=0;r<4;r++){
    float mx = -1e30f;
    #pragma unroll
    for (int ni=0;ni<8;ni++){
      float s = accS[ni][r] * 0.125f;
      if (tk[ni] == tq[r]) s = -50000.0f;
      accS[ni][r] = s;
      mx = fmaxf(mx, s);
    }
    mx = fmaxf(mx, __shfl_xor(mx, 1));
    mx = fmaxf(mx, __shfl_xor(mx, 2));
    mx = fmaxf(mx, __shfl_xor(mx, 4));
    mx = fmaxf(mx, __shfl_xor(mx, 8));
    mrow[r] = mx;
    float ls = 0.f;
    #pragma unroll
    for (int ni=0;ni<8;ni++){
      float e = __expf(accS[ni][r] - mx);
      accS[ni][r] = e;
      ls += e;
    }
    ls += __shfl_xor(ls, 1);
    ls += __shfl_xor(ls, 2);
    ls += __shfl_xor(ls, 4);
    ls += __shfl_xor(ls, 8);
    lrow[r] = ls;
  }

  // all waves done reading k_lds (aliased with p_lds) before any P write
  __syncthreads();

  #pragma unroll
  for (int ni=0;ni<8;ni++)
    #pragma unroll
    for (int r=0;r<4;r++)
      p_lds[(mi*16 + quad*4 + r)*PSTRIDE + ni*16 + c_lane] = (f16)accS[ni][r];

  // wave reads only its own P rows -> no cross-wave barrier needed
  f16x8 pa[4];
  #pragma unroll
  for (int kb=0;kb<4;kb++)
    pa[kb] = *(const f16x8*)&p_lds[(mi*16 + c_lane)*PSTRIDE + kb*32 + quad*8];

  size_t rowbase = (size_t)(bh*NHASH + h)*T_SZ;
  #pragma unroll
  for (int ni2=0;ni2<4;ni2++){
    f16x8 bv[4];
    #pragma unroll
    for (int kb=0;kb<4;kb++)
      bv[kb] = *(const f16x8*)&vT[(ni2*16 + c_lane)*PSTRIDE + kb*32 + quad*8];
    f32x4 accO = (f32x4){0.f,0.f,0.f,0.f};
    #pragma unroll
    for (int kb=0;kb<4;kb++)
      accO = __builtin_amdgcn_mfma_f32_16x16x32_f16(pa[kb], bv[kb], accO, 0,0,0);
    #pragma unroll
    for (int r=0;r<4;r++){
      float invl = 1.0f / lrow[r];
      f16* orow = o_out + (rowbase + tq[r])*DH;
      orow[ni2*16 + c_lane] = (f16)(accO[r] * invl);
    }
  }
  #pragma unroll
  for (int r=0;r<4;r++){
    if (c_lane == 0)
      lse_out[rowbase + tq[r]] = mrow[r] + logf(lrow[r]);
  }
}

// ---------------- K5: combine hash rounds -> X_hi/X_lo (f16 split) ----------
__global__ __launch_bounds__(256) void k5_comb(const float* __restrict__ lse,
    const f16* __restrict__ o_f16, f16* __restrict__ Xh, f16* __restrict__ Xl)
{
  int gid = blockIdx.x*256 + threadIdx.x;  // [0, BH*T)
  int t = gid & (T_SZ-1);
  int bh = gid >> 12;
  size_t base = (size_t)bh*NHASH*T_SZ + t;
  float l0 = lse[base];
  float l1 = lse[base + T_SZ];
  float l2 = lse[base + 2*T_SZ];
  float l3 = lse[base + 3*T_SZ];
  float M = fmaxf(fmaxf(l0,l1), fmaxf(l2,l3));
  float e0 = __expf(l0-M), e1 = __expf(l1-M), e2 = __expf(l2-M), e3 = __expf(l3-M);
  float inv = 1.0f/(e0+e1+e2+e3);
  float w0=e0*inv, w1=e1*inv, w2=e2*inv, w3=e3*inv;
  const f16x8* r0 = (const f16x8*)(o_f16 + base*DH);
  const f16x8* r1 = (const f16x8*)(o_f16 + (base + (size_t)T_SZ)*DH);
  const f16x8* r2 = (const f16x8*)(o_f16 + (base + (size_t)2*T_SZ)*DH);
  const f16x8* r3 = (const f16x8*)(o_f16 + (base + (size_t)3*T_SZ)*DH);
  int b = bh >> 3, head = bh & 7;
  size_t xofs = ((size_t)(b*T_SZ + t)*DMODEL + head*DH);
  f16x8* xh = (f16x8*)(Xh + xofs);
  f16x8* xl = (f16x8*)(Xl + xofs);
  #pragma unroll
  for (int i=0; i<8; i++){
    f16x8 a = r0[i], bb = r1[i], cc = r2[i], dd = r3[i];
    f16x8 ho, lo;
    #pragma unroll
    for (int e=0;e<8;e++){
      float res = w0*(float)a[e] + w1*(float)bb[e] + w2*(float)cc[e] + w3*(float)dd[e];
      f16 hh = (f16)res;
      ho[e] = hh; lo[e] = (f16)(res - (float)hh);
    }
    xh[i] = ho; xl[i] = lo;
  }
}

// ---------------- launch ----------------
extern "C" void kernel_launch(void* const* d_in, const int* in_sizes, int n_in,
                              void* d_out, int out_size, void* d_ws, size_t ws_size,
                              hipStream_t stream) {
  const float* queries = (const float*)d_in[0];
  const float* Wqk     = (const float*)d_in[3];
  const float* Wv      = (const float*)d_in[4];
  const float* Wout    = (const float*)d_in[5];
  const float* bout    = (const float*)d_in[6];
  const float* rot     = (const float*)d_in[7];
  float* out = (float*)d_out;

  const size_t SZ_F16  = (size_t)BH*T_SZ*DH*2;        // 16 MB
  const size_t SZ_WT   = (size_t)1536*512*2;          // 1.5 MB
  const size_t SZ_ROT  = (size_t)128*64*2;            // 16 KB
  const size_t SZ_O    = (size_t)BH*NHASH*T_SZ*DH*2;  // 64 MB
  const size_t OFS_X      = 0;
  const size_t OFS_AH     = OFS_X    + 2*SZ_F16;
  const size_t OFS_AL     = OFS_AH   + SZ_F16;
  const size_t OFS_QK16   = OFS_AL   + SZ_F16;
  const size_t OFS_V16    = OFS_QK16 + SZ_F16;
  const size_t OFS_WTH    = OFS_V16  + SZ_F16;
  const size_t OFS_WTL    = OFS_WTH  + SZ_WT;
  const size_t OFS_ROTH   = OFS_WTL  + SZ_WT;
  const size_t OFS_ROTL   = OFS_ROTH + SZ_ROT;
  const size_t OFS_O      = OFS_ROTL + SZ_ROT;
  const size_t OFS_BUCKET = OFS_O    + SZ_O;
  const size_t OFS_HIST   = OFS_BUCKET + (size_t)BH*NHASH*T_SZ*2;
  const size_t OFS_STARTS = OFS_HIST   + (size_t)BH*NBUCK*4;
  const size_t OFS_ST     = OFS_STARTS + (size_t)BH*NBUCK*4;
  const size_t OFS_LSE    = OFS_ST     + (size_t)BH*TOT*4;
  const size_t OFS_AMB    = OFS_LSE    + (size_t)BH*NHASH*T_SZ*4;
  const size_t OFS_CNT    = OFS_AMB    + (size_t)BH*NHASH*T_SZ*4;
  const size_t WS_NEEDED  = OFS_CNT    + 256;
  if (ws_size < WS_NEEDED) return;

  char* ws = (char*)d_ws;
  f16*      qkl    = (f16*)(ws + OFS_X);               // alias with Xh (disjoint lifetime)
  f16*      Xh     = (f16*)(ws + OFS_X);
  f16*      Xl     = (f16*)(ws + OFS_X + SZ_F16);
  f16*      Ah     = (f16*)(ws + OFS_AH);
  f16*      Al     = (f16*)(ws + OFS_AL);
  f16*      qk16   = (f16*)(ws + OFS_QK16);
  f16*      v16    = (f16*)(ws + OFS_V16);
  f16*      Wth    = (f16*)(ws + OFS_WTH);
  f16*      Wtl    = (f16*)(ws + OFS_WTL);
  f16*      rotTh  = (f16*)(ws + OFS_ROTH);
  f16*      rotTl  = (f16*)(ws + OFS_ROTL);
  f16*      o_f16  = (f16*)(ws + OFS_O);
  unsigned short* bucket = (unsigned short*)(ws + OFS_BUCKET);
  int*      hist   = (int*)(ws + OFS_HIST);
  int*      starts = (int*)(ws + OFS_STARTS);
  int*      st     = (int*)(ws + OFS_ST);
  float*    lse    = (float*)(ws + OFS_LSE);
  int*      amb    = (int*)(ws + OFS_AMB);
  int*      cnt    = (int*)(ws + OFS_CNT);

  k0_zero   <<<BH, 256, 0, stream>>>(hist, cnt);
  kw_t      <<<(1536*512)/256, 256, 0, stream>>>(Wqk, Wv, Wout, Wth, Wtl);
  kr_t      <<<(128*64)/256, 256, 0, stream>>>(rot, rotTh, rotTl);
  k1a_split <<<(M_TOK*DMODEL/8)/256, 256, 0, stream>>>(queries, Ah, Al);
  g_qkv     <<<dim3(M_TOK/128, 8), 256, 0, stream>>>(Ah, Al, Wth, Wtl, qk16, qkl, v16);
  k2_mfma   <<<(BH*T_SZ)/128, 256, 0, stream>>>(qk16, qkl, rotTh, rotTl, bucket, hist, amb, cnt);
  k2_fix    <<<2048, 64, 0, stream>>>(queries, Wqk, rot, amb, cnt, bucket, hist);
  k3_scan   <<<BH, 256, 0, stream>>>(hist, starts);
  k3b_scatter<<<BH*NBUCK, 64, 0, stream>>>(bucket, starts, st);
  k4_attn   <<<BH*256, 256, 0, stream>>>(qk16, v16, st, lse, o_f16);
  k5_comb   <<<(BH*T_SZ)/256, 256, 0, stream>>>(lse, o_f16, Xh, Xl);
  g_out     <<<dim3(M_TOK/128, 4), 256, 0, stream>>>(Xh, Xl, Wth, Wtl, bout, out);
}

// Round 2
// 491.479 us; speedup vs baseline: 1.0869x; 1.0702x over previous
//
#include <hip/hip_runtime.h>

typedef unsigned int uint32;
typedef _Float16 f16;
typedef _Float16 f16x8 __attribute__((ext_vector_type(8)));
typedef float f32x4 __attribute__((ext_vector_type(4)));
typedef unsigned short u16x8 __attribute__((ext_vector_type(8)));

#define B_SZ 4
#define T_SZ 4096
#define DMODEL 512
#define NHEAD 8
#define DH 64
#define NHASH 4
#define BH (B_SZ*NHEAD)      // 32
#define NBUCK 256
#define TOT (NHASH*T_SZ)     // 16384
#define M_TOK (B_SZ*T_SZ)    // 16384

#define KSTRIDE 72           // f16 elems per LDS row (128B data + 16B pad)
#define PSTRIDE 136

// split-f16 MFMA hash-score worst-case error ~4e-5*rms; keep >=35x margin.
#define AMB_TAU 1.5e-3f

// ---------------- K0: zero ambiguity counter ----------------
__global__ void k0_zero(int* amb_cnt){
  if (threadIdx.x == 0 && blockIdx.x == 0) *amb_cnt = 0;
}

// ---------------- KW: transpose + split W matrices into Wt[n][k] f16 hi/lo ----
__global__ __launch_bounds__(256) void kw_t(const float* __restrict__ Wqk,
    const float* __restrict__ Wv, const float* __restrict__ Wout,
    f16* __restrict__ Wth, f16* __restrict__ Wtl)
{
  int gid = blockIdx.x*256 + threadIdx.x;   // [0, 1536*512)
  int n = gid >> 9, k = gid & 511;
  int sel = n >> 9, col = n & 511;
  const float* src = (sel==0)? Wqk : (sel==1)? Wv : Wout;
  float v = src[(size_t)k*512 + col];
  f16 h = (f16)v;
  Wth[gid] = h;
  Wtl[gid] = (f16)(v - (float)h);
}

// ---------------- KR: transpose + split rotations into rotT[n=h*32+j][k=dd] --
__global__ __launch_bounds__(256) void kr_t(const float* __restrict__ rot,
    f16* __restrict__ rotTh, f16* __restrict__ rotTl)
{
  int gid = blockIdx.x*256 + threadIdx.x;   // [0, 128*64)
  int n = gid >> 6, dd = gid & 63;
  float v = rot[dd*128 + n];
  f16 h = (f16)v;
  rotTh[gid] = h;
  rotTl[gid] = (f16)(v - (float)h);
}

// ---------------- K1a: split queries (f32) -> A_hi/A_lo (f16) ----------------
__global__ __launch_bounds__(256) void k1a_split(const float* __restrict__ qin,
    f16* __restrict__ Ah, f16* __restrict__ Al)
{
  size_t gid = (size_t)blockIdx.x*256 + threadIdx.x;   // handles 8 floats
  const float4* src = (const float4*)(qin) + gid*2;
  float4 x0 = src[0], x1 = src[1];
  float v[8] = {x0.x,x0.y,x0.z,x0.w, x1.x,x1.y,x1.z,x1.w};
  f16x8 h, l;
  #pragma unroll
  for (int e=0;e<8;e++){ f16 hh=(f16)v[e]; h[e]=hh; l[e]=(f16)(v[e]-(float)hh); }
  ((f16x8*)Ah)[gid] = h;
  ((f16x8*)Al)[gid] = l;
}

// ---------------- G1: split-f16 MFMA GEMM  qk|v = queries @ [Wqk|Wv] ---------
__global__ __launch_bounds__(256) void g_qkv(const f16* __restrict__ Ah,
    const f16* __restrict__ Al, const f16* __restrict__ Wth, const f16* __restrict__ Wtl,
    f16* __restrict__ qk16, f16* __restrict__ qkl, f16* __restrict__ v16)
{
  __shared__ f16 ah[128*KSTRIDE], al[128*KSTRIDE], bh[128*KSTRIDE], bl[128*KSTRIDE];
  int tid = threadIdx.x;
  int m0 = blockIdx.x*128, n0 = blockIdx.y*128;
  int w = tid >> 6, lane = tid & 63;
  int wm = w >> 1, wn = w & 1;
  int c_lane = lane & 15, quad = lane >> 4;

  f32x4 acc[4][4];
  #pragma unroll
  for (int mi=0;mi<4;mi++)
    #pragma unroll
    for (int ni=0;ni<4;ni++) acc[mi][ni] = (f32x4){0.f,0.f,0.f,0.f};

  int sr = tid >> 1, sc = (tid & 1) * 32;
  for (int kc=0; kc<8; kc++){
    int k0 = kc*64;
    {
      const f16x8* pah = (const f16x8*)(Ah + (size_t)(m0+sr)*512 + k0 + sc);
      const f16x8* pal = (const f16x8*)(Al + (size_t)(m0+sr)*512 + k0 + sc);
      const f16x8* pbh = (const f16x8*)(Wth + (size_t)(n0+sr)*512 + k0 + sc);
      const f16x8* pbl = (const f16x8*)(Wtl + (size_t)(n0+sr)*512 + k0 + sc);
      f16x8* dah = (f16x8*)&ah[sr*KSTRIDE + sc];
      f16x8* dal = (f16x8*)&al[sr*KSTRIDE + sc];
      f16x8* dbh = (f16x8*)&bh[sr*KSTRIDE + sc];
      f16x8* dbl = (f16x8*)&bl[sr*KSTRIDE + sc];
      #pragma unroll
      for (int i=0;i<4;i++){ dah[i]=pah[i]; dal[i]=pal[i]; dbh[i]=pbh[i]; dbl[i]=pbl[i]; }
    }
    __syncthreads();
    f16x8 fah[4][2], fal[4][2], fbh[4][2], fbl[4][2];
    #pragma unroll
    for (int i=0;i<4;i++)
      #pragma unroll
      for (int kb=0;kb<2;kb++){
        int ma = (wm*64 + i*16 + c_lane)*KSTRIDE + kb*32 + quad*8;
        int nb = (wn*64 + i*16 + c_lane)*KSTRIDE + kb*32 + quad*8;
        fah[i][kb] = *(const f16x8*)&ah[ma];
        fal[i][kb] = *(const f16x8*)&al[ma];
        fbh[i][kb] = *(const f16x8*)&bh[nb];
        fbl[i][kb] = *(const f16x8*)&bl[nb];
      }
    #pragma unroll
    for (int kb=0;kb<2;kb++)
      #pragma unroll
      for (int p=0;p<3;p++)
        #pragma unroll
        for (int mi=0;mi<4;mi++)
          #pragma unroll
          for (int ni=0;ni<4;ni++){
            f16x8 a = (p==2)? fal[mi][kb] : fah[mi][kb];
            f16x8 b = (p==1)? fbl[ni][kb] : fbh[ni][kb];
            acc[mi][ni] = __builtin_amdgcn_mfma_f32_16x16x32_f16(a, b, acc[mi][ni], 0,0,0);
          }
    __syncthreads();
  }

  // epilogue: n<512 -> qk16(hi)+qkl(lo); n>=512 -> v16
  #pragma unroll
  for (int mi=0;mi<4;mi++)
    #pragma unroll
    for (int ni=0;ni<4;ni++)
      #pragma unroll
      for (int r=0;r<4;r++){
        int n = n0 + wn*64 + ni*16 + c_lane;
        int tok = m0 + wm*64 + mi*16 + quad*4 + r;
        float val = acc[mi][ni][r];
        int b = tok >> 12, tp = tok & 4095;
        if (n < 512){
          int head = n >> 6, dd = n & 63;
          size_t idx = ((size_t)(b*NHEAD+head)*T_SZ + tp)*DH + dd;
          f16 hv = (f16)val;
          qk16[idx] = hv;
          qkl[idx]  = (f16)(val - (float)hv);
        } else {
          int j = n - 512, head = j >> 6, dd = j & 63;
          size_t idx = ((size_t)(b*NHEAD+head)*T_SZ + tp)*DH + dd;
          v16[idx] = (f16)val;
        }
      }
}

// ---------------- G2: split-f16 MFMA GEMM  out = X @ Wout + bias -------------
__global__ __launch_bounds__(256) void g_out(const f16* __restrict__ Xh,
    const f16* __restrict__ Xl, const f16* __restrict__ Wth, const f16* __restrict__ Wtl,
    const float* __restrict__ bout, float* __restrict__ out)
{
  __shared__ f16 ah[128*KSTRIDE], al[128*KSTRIDE], bh[128*KSTRIDE], bl[128*KSTRIDE];
  int tid = threadIdx.x;
  int m0 = blockIdx.x*128, n0 = blockIdx.y*128;
  int w = tid >> 6, lane = tid & 63;
  int wm = w >> 1, wn = w & 1;
  int c_lane = lane & 15, quad = lane >> 4;
  const f16* Bh_base = Wth + (size_t)1024*512;   // Wout section
  const f16* Bl_base = Wtl + (size_t)1024*512;

  f32x4 acc[4][4];
  #pragma unroll
  for (int mi=0;mi<4;mi++)
    #pragma unroll
    for (int ni=0;ni<4;ni++) acc[mi][ni] = (f32x4){0.f,0.f,0.f,0.f};

  int sr = tid >> 1, sc = (tid & 1) * 32;
  for (int kc=0; kc<8; kc++){
    int k0 = kc*64;
    {
      const f16x8* pah = (const f16x8*)(Xh + (size_t)(m0+sr)*512 + k0 + sc);
      const f16x8* pal = (const f16x8*)(Xl + (size_t)(m0+sr)*512 + k0 + sc);
      const f16x8* pbh = (const f16x8*)(Bh_base + (size_t)(n0+sr)*512 + k0 + sc);
      const f16x8* pbl = (const f16x8*)(Bl_base + (size_t)(n0+sr)*512 + k0 + sc);
      f16x8* dah = (f16x8*)&ah[sr*KSTRIDE + sc];
      f16x8* dal = (f16x8*)&al[sr*KSTRIDE + sc];
      f16x8* dbh = (f16x8*)&bh[sr*KSTRIDE + sc];
      f16x8* dbl = (f16x8*)&bl[sr*KSTRIDE + sc];
      #pragma unroll
      for (int i=0;i<4;i++){ dah[i]=pah[i]; dal[i]=pal[i]; dbh[i]=pbh[i]; dbl[i]=pbl[i]; }
    }
    __syncthreads();
    f16x8 fah[4][2], fal[4][2], fbh[4][2], fbl[4][2];
    #pragma unroll
    for (int i=0;i<4;i++)
      #pragma unroll
      for (int kb=0;kb<2;kb++){
        int ma = (wm*64 + i*16 + c_lane)*KSTRIDE + kb*32 + quad*8;
        int nb = (wn*64 + i*16 + c_lane)*KSTRIDE + kb*32 + quad*8;
        fah[i][kb] = *(const f16x8*)&ah[ma];
        fal[i][kb] = *(const f16x8*)&al[ma];
        fbh[i][kb] = *(const f16x8*)&bh[nb];
        fbl[i][kb] = *(const f16x8*)&bl[nb];
      }
    #pragma unroll
    for (int kb=0;kb<2;kb++)
      #pragma unroll
      for (int p=0;p<3;p++)
        #pragma unroll
        for (int mi=0;mi<4;mi++)
          #pragma unroll
          for (int ni=0;ni<4;ni++){
            f16x8 a = (p==2)? fal[mi][kb] : fah[mi][kb];
            f16x8 b = (p==1)? fbl[ni][kb] : fbh[ni][kb];
            acc[mi][ni] = __builtin_amdgcn_mfma_f32_16x16x32_f16(a, b, acc[mi][ni], 0,0,0);
          }
    __syncthreads();
  }

  #pragma unroll
  for (int mi=0;mi<4;mi++)
    #pragma unroll
    for (int ni=0;ni<4;ni++){
      int n = n0 + wn*64 + ni*16 + c_lane;
      float bn = bout[n];
      #pragma unroll
      for (int r=0;r<4;r++){
        int tok = m0 + wm*64 + mi*16 + quad*4 + r;
        out[(size_t)tok*512 + n] = acc[mi][ni][r] + bn;
      }
    }
}

// ---------------- K2: LSH hashing, rot-as-A MFMA + in-lane argmax epilogue ----
// v3: operands swapped (A = rotT so D rows = rotation outputs j, D cols =
// tokens). Each lane holds 8 of the 32 candidates per hash in-register;
// argmax needs only a 2-step cross-quad shfl (32 bpermutes/wave vs 512).
// NO global hist atomics (the 524K device-scope atomicAdds were the 109us
// bottleneck: 33MB of 64B far-atomic RMW == measured FETCH+WRITE). Histogram
// is recomputed from `bucket` in k3_scan via LDS atomics.
__global__ __launch_bounds__(256, 4) void k2_mfma(const f16* __restrict__ qkh,
    const f16* __restrict__ qkl, const f16* __restrict__ rotTh, const f16* __restrict__ rotTl,
    unsigned short* __restrict__ bucket,
    int* __restrict__ amb_list, int* __restrict__ amb_cnt)
{
  int tid = threadIdx.x;
  int w = tid >> 6, lane = tid & 63;
  int c_lane = lane & 15, quad = lane >> 4;
  int tok0 = (blockIdx.x*4 + w)*16;            // 16 tokens per wave
  size_t rowb = (size_t)(tok0 + c_lane)*64;

  // B fragments: token hi/lo (col = token = c_lane, k = kb*32 + quad*8 + e)
  f16x8 tbh[2], tbl[2];
  #pragma unroll
  for (int kb=0;kb<2;kb++){
    tbh[kb] = *(const f16x8*)&qkh[rowb + kb*32 + quad*8];
    tbl[kb] = *(const f16x8*)&qkl[rowb + kb*32 + quad*8];
  }

  f32x4 acc[8];
  #pragma unroll
  for (int mi=0;mi<8;mi++) acc[mi] = (f32x4){0.f,0.f,0.f,0.f};

  // A fragments: rot rows j = mi*16 + c_lane (L1-resident, 32KB total)
  #pragma unroll
  for (int mi=0;mi<8;mi++){
    int aoff = (mi*16 + c_lane)*64;
    #pragma unroll
    for (int kb=0;kb<2;kb++){
      f16x8 arh = *(const f16x8*)&rotTh[aoff + kb*32 + quad*8];
      f16x8 arl = *(const f16x8*)&rotTl[aoff + kb*32 + quad*8];
      acc[mi] = __builtin_amdgcn_mfma_f32_16x16x32_f16(arh, tbh[kb], acc[mi], 0,0,0);
      acc[mi] = __builtin_amdgcn_mfma_f32_16x16x32_f16(arl, tbh[kb], acc[mi], 0,0,0);
      acc[mi] = __builtin_amdgcn_mfma_f32_16x16x32_f16(arh, tbl[kb], acc[mi], 0,0,0);
    }
  }

  // lane (c_lane, quad) holds scores s[j] for token tok0+c_lane,
  // j = mi*16 + quad*4 + r  (mi = 0..7, r = 0..3)
  int tokg = tok0 + c_lane;
  int bhh = tokg >> 12, t = tokg & 4095;

  #pragma unroll
  for (int h=0; h<4; h++){
    float m1 = -1e30f, m2 = -1e30f, ssq = 0.f; int b1 = 0;
    #pragma unroll
    for (int u=0; u<8; u++){
      float v = acc[2*h + (u>>2)][u&3];
      int bidd = (u>>2)*16 + quad*4 + (u&3);   // within-hash index [0,32)
      ssq += v*v;
      if (v > m1){ m2=m1; m1=v; b1=bidd; } else if (v > m2) m2=v;
      float nv = -v;
      if (nv > m1){ m2=m1; m1=nv; b1=bidd+32; } else if (nv > m2) m2=nv;
    }
    // cross-quad reduce (lane bits 4,5)
    #pragma unroll
    for (int d2=16; d2<64; d2<<=1){
      float om1 = __shfl_xor(m1, d2);
      float om2 = __shfl_xor(m2, d2);
      int   ob1 = __shfl_xor(b1, d2);
      ssq += __shfl_xor(ssq, d2);
      if (om1 > m1){ m2 = fmaxf(m1, om2); m1 = om1; b1 = ob1; }
      else          { m2 = fmaxf(m2, om1); }
    }
    if (quad == 0){
      float rms = sqrtf(ssq * (1.0f/32.0f));
      if (m1 - m2 < AMB_TAU * rms){
        int idx = atomicAdd(amb_cnt, 1);
        amb_list[idx] = (bhh<<14) | (h<<12) | t;
      } else {
        bucket[((bhh*NHASH + h)<<12) + t] = (unsigned short)(b1 + (h<<6));
      }
    }
  }
}

// ---------------- K2fix: exact f64 recompute for ambiguous decisions ----------
__global__ __launch_bounds__(64) void k2_fix(const float* __restrict__ qin,
    const float* __restrict__ Wqk, const float* __restrict__ rot,
    const int* __restrict__ amb_list, const int* __restrict__ amb_cnt,
    unsigned short* __restrict__ bucket)
{
  __shared__ __align__(16) float qs[512];
  __shared__ double qk64[64];
  __shared__ double accs[32];
  int n = *amb_cnt;
  int lane = threadIdx.x;
  for (int it = blockIdx.x; it < n; it += gridDim.x){
    int gid = amb_list[it];
    int t = gid & (T_SZ-1);
    int h = (gid >> 12) & 3;
    int bh = gid >> 14;
    int b = bh >> 3, head = bh & 7;
    const float4* qrow4 = (const float4*)(qin + ((size_t)b*T_SZ + t)*DMODEL);
    float4 x0 = qrow4[lane];
    float4 x1 = qrow4[lane + 64];
    *(float4*)&qs[lane*4]       = x0;
    *(float4*)&qs[256 + lane*4] = x1;
    __syncthreads();
    const float* wcol = Wqk + head*64 + lane;
    double s = 0.0;
    #pragma unroll 16
    for (int d=0; d<512; d++)
      s += (double)qs[d] * (double)wcol[(size_t)d*512];
    qk64[lane] = s;
    __syncthreads();
    if (lane < 32){
      double a = 0.0;
      #pragma unroll 16
      for (int f=0; f<64; f++)
        a += qk64[f] * (double)rot[f*(NHASH*32) + h*32 + lane];
      accs[lane] = a;
    }
    __syncthreads();
    if (lane == 0){
      double best = accs[0]; int bk = 0;
      for (int k=1;k<64;k++){
        double vv = (k<32)? accs[k] : -accs[k-32];
        if (vv > best){ best = vv; bk = k; }
      }
      int g = bk + (h<<6);
      bucket[((bh*NHASH + h)<<12) + t] = (unsigned short)g;
    }
    __syncthreads();
  }
}

// ---------------- K3: LDS histogram from bucket + exclusive prefix scan -------
__global__ __launch_bounds__(256) void k3_scan(const unsigned short* __restrict__ bucket,
    int* __restrict__ starts){
  __shared__ int s[256];
  int bh = blockIdx.x, tid = threadIdx.x;
  s[tid] = 0;
  __syncthreads();
  const u16x8* b8 = (const u16x8*)(bucket + ((size_t)bh*NHASH << 12));
  for (int i = tid; i < 2048; i += 256){   // 16384 u16 = 2048 x u16x8
    u16x8 x = b8[i];
    #pragma unroll
    for (int e=0;e<8;e++) atomicAdd(&s[x[e]], 1);
  }
  __syncthreads();
  int v = s[tid];
  __syncthreads();
  for (int off=1; off<256; off<<=1){
    int a = (tid >= off) ? s[tid-off] : 0;
    __syncthreads();
    s[tid] += a;
    __syncthreads();
  }
  starts[bh*256 + tid] = s[tid] - v;
}

// ---------------- K3b: stable counting-sort scatter ----------------
__global__ __launch_bounds__(64) void k3b_scatter(const unsigned short* __restrict__ bucket,
    const int* __restrict__ starts, int* __restrict__ st)
{
  int blk = blockIdx.x;
  int bh = blk >> 8; int g = blk & 255; int h = g >> 6;
  int lane = threadIdx.x;
  const unsigned short* brow = bucket + ((bh*NHASH + h)<<12);
  int base = starts[bh*NBUCK + g];
  for (int step=0; step<64; step++){
    int t = step*64 + lane;
    bool pred = (brow[t] == (unsigned short)g);
    unsigned long long mask = __ballot(pred);
    if (pred){
      int off = __popcll(mask & ((1ull<<lane) - 1ull));
      st[bh*TOT + base + off] = t;
    }
    base += __popcll(mask);
  }
}

// ---------------- K4: MFMA chunked LSH attention ------------------------------
// 4 cooperative waves per chunk (wave w owns query sub-tile mi=w).
// 36864B LDS -> 4 blocks/CU at 256 thr = 16 waves/CU. XCD-aware swizzle.
__global__ __launch_bounds__(256, 4) void k4_attn(const f16* __restrict__ qk16,
    const f16* __restrict__ v16, const int* __restrict__ st,
    float* __restrict__ lse_out, f16* __restrict__ o_out)
{
  __shared__ __align__(16) char smem[36864];
  f16*   k_lds   = (f16*)smem;                 // 128 x KSTRIDE (alias p_lds)
  f16*   p_lds   = (f16*)smem;                 // 64 x PSTRIDE
  f16*   vT      = (f16*)(smem + 18432);       // 64 x PSTRIDE (d-major)
  float* invnorm = (float*)(smem + 35840);
  int*   kv_t    = (int*)(smem + 36352);

  int bid = blockIdx.x;
  int swz = (bid & 7) * 1024 + (bid >> 3);     // bijective: 8192 = 8*1024
  int bh = swz >> 8; int c = swz & 255;
  int h = c >> 6; int cp = (c + 255) & 255;
  int tid = threadIdx.x;
  int w = tid >> 6, lane = tid & 63;
  int c_lane = lane & 15, quad = lane >> 4;
  const int* strow = st + bh*TOT;

  // ---- load phase: threads 0..127, one full K/V row each
  if (tid < 128){
    int row = tid;
    int slot = (row < 64) ? (c*64 + row) : (cp*64 + row - 64);
    int t = strow[slot];
    kv_t[row] = t;
    const f16x8* kr = (const f16x8*)(qk16 + ((size_t)bh*T_SZ + t)*DH);
    const f16x8* vr = (const f16x8*)(v16  + ((size_t)bh*T_SZ + t)*DH);
    f16x8 kv[8], vv[8];
    float ss = 0.f;
    #pragma unroll
    for (int i=0;i<8;i++){
      f16x8 x = kr[i]; kv[i] = x;
      vv[i] = vr[i];
      #pragma unroll
      for (int e=0;e<8;e++){ float f = (float)x[e]; ss += f*f; }
    }
    invnorm[row] = 1.0f / fmaxf(sqrtf(ss), 1e-12f);
    f16x8* kd = (f16x8*)&k_lds[row*KSTRIDE];
    #pragma unroll
    for (int i=0;i<8;i++) kd[i] = kv[i];
    #pragma unroll
    for (int i=0;i<8;i++){
      #pragma unroll
      for (int e=0;e<8;e++) vT[(i*8+e)*PSTRIDE + row] = vv[i][e];
    }
  }
  __syncthreads();

  // ---- QK^T: wave w computes query sub-tile mi = w ----
  int mi = w;
  f16x8 aq[2];
  #pragma unroll
  for (int kb=0;kb<2;kb++)
    aq[kb] = *(const f16x8*)&k_lds[(mi*16 + c_lane)*KSTRIDE + kb*32 + quad*8];

  f32x4 accS[8];
  #pragma unroll
  for (int ni=0;ni<8;ni++) accS[ni] = (f32x4){0.f,0.f,0.f,0.f};

  #pragma unroll
  for (int ni=0;ni<8;ni++){
    int rowb = ni*16 + c_lane;
    f16 sc = (f16)invnorm[rowb];
    f16x8 b0 = *(const f16x8*)&k_lds[rowb*KSTRIDE + 0*32 + quad*8];
    f16x8 b1 = *(const f16x8*)&k_lds[rowb*KSTRIDE + 1*32 + quad*8];
    b0 *= sc; b1 *= sc;
    accS[ni] = __builtin_amdgcn_mfma_f32_16x16x32_f16(aq[0], b0, accS[ni], 0,0,0);
    accS[ni] = __builtin_amdgcn_mfma_f32_16x16x32_f16(aq[1], b1, accS[ni], 0,0,0);
  }

  int tq[4];
  #pragma unroll
  for (int r=0;r<4;r++) tq[r] = kv_t[mi*16 + quad*4 + r];
  int tk[8];
  #pragma unroll
  for (int ni=0;ni<8;ni++) tk[ni] = kv_t[ni*16 + c_lane];

  float mrow[4], lrow[4];
  #pragma unroll
  for (int r=0;r<4;r++){
    float mx = -1e30f;
    #pragma unroll
    for (int ni=0;ni<8;ni++){
      float s = accS[ni][r] * 0.125f;
      if (tk[ni] == tq[r]) s = -50000.0f;
      accS[ni][r] = s;
      mx = fmaxf(mx, s);
    }
    mx = fmaxf(mx, __shfl_xor(mx, 1));
    mx = fmaxf(mx, __shfl_xor(mx, 2));
    mx = fmaxf(mx, __shfl_xor(mx, 4));
    mx = fmaxf(mx, __shfl_xor(mx, 8));
    mrow[r] = mx;
    float ls = 0.f;
    #pragma unroll
    for (int ni=0;ni<8;ni++){
      float e = __expf(accS[ni][r] - mx);
      accS[ni][r] = e;
      ls += e;
    }
    ls += __shfl_xor(ls, 1);
    ls += __shfl_xor(ls, 2);
    ls += __shfl_xor(ls, 4);
    ls += __shfl_xor(ls, 8);
    lrow[r] = ls;
  }

  // all waves done reading k_lds (aliased with p_lds) before any P write
  __syncthreads();

  #pragma unroll
  for (int ni=0;ni<8;ni++)
    #pragma unroll
    for (int r=0;r<4;r++)
      p_lds[(mi*16 + quad*4 + r)*PSTRIDE + ni*16 + c_lane] = (f16)accS[ni][r];

  // wave reads only its own P rows -> no cross-wave barrier needed
  f16x8 pa[4];
  #pragma unroll
  for (int kb=0;kb<4;kb++)
    pa[kb] = *(const f16x8*)&p_lds[(mi*16 + c_lane)*PSTRIDE + kb*32 + quad*8];

  size_t rowbase = (size_t)(bh*NHASH + h)*T_SZ;
  #pragma unroll
  for (int ni2=0;ni2<4;ni2++){
    f16x8 bv[4];
    #pragma unroll
    for (int kb=0;kb<4;kb++)
      bv[kb] = *(const f16x8*)&vT[(ni2*16 + c_lane)*PSTRIDE + kb*32 + quad*8];
    f32x4 accO = (f32x4){0.f,0.f,0.f,0.f};
    #pragma unroll
    for (int kb=0;kb<4;kb++)
      accO = __builtin_amdgcn_mfma_f32_16x16x32_f16(pa[kb], bv[kb], accO, 0,0,0);
    #pragma unroll
    for (int r=0;r<4;r++){
      float invl = 1.0f / lrow[r];
      f16* orow = o_out + (rowbase + tq[r])*DH;
      orow[ni2*16 + c_lane] = (f16)(accO[r] * invl);
    }
  }
  #pragma unroll
  for (int r=0;r<4;r++){
    if (c_lane == 0)
      lse_out[rowbase + tq[r]] = mrow[r] + logf(lrow[r]);
  }
}

// ---------------- K5: combine hash rounds -> X_hi/X_lo (f16 split) ----------
__global__ __launch_bounds__(256) void k5_comb(const float* __restrict__ lse,
    const f16* __restrict__ o_f16, f16* __restrict__ Xh, f16* __restrict__ Xl)
{
  int gid = blockIdx.x*256 + threadIdx.x;  // [0, BH*T)
  int t = gid & (T_SZ-1);
  int bh = gid >> 12;
  size_t base = (size_t)bh*NHASH*T_SZ + t;
  float l0 = lse[base];
  float l1 = lse[base + T_SZ];
  float l2 = lse[base + 2*T_SZ];
  float l3 = lse[base + 3*T_SZ];
  float M = fmaxf(fmaxf(l0,l1), fmaxf(l2,l3));
  float e0 = __expf(l0-M), e1 = __expf(l1-M), e2 = __expf(l2-M), e3 = __expf(l3-M);
  float inv = 1.0f/(e0+e1+e2+e3);
  float w0=e0*inv, w1=e1*inv, w2=e2*inv, w3=e3*inv;
  const f16x8* r0 = (const f16x8*)(o_f16 + base*DH);
  const f16x8* r1 = (const f16x8*)(o_f16 + (base + (size_t)T_SZ)*DH);
  const f16x8* r2 = (const f16x8*)(o_f16 + (base + (size_t)2*T_SZ)*DH);
  const f16x8* r3 = (const f16x8*)(o_f16 + (base + (size_t)3*T_SZ)*DH);
  int b = bh >> 3, head = bh & 7;
  size_t xofs = ((size_t)(b*T_SZ + t)*DMODEL + head*DH);
  f16x8* xh = (f16x8*)(Xh + xofs);
  f16x8* xl = (f16x8*)(Xl + xofs);
  #pragma unroll
  for (int i=0; i<8; i++){
    f16x8 a = r0[i], bb = r1[i], cc = r2[i], dd = r3[i];
    f16x8 ho, lo;
    #pragma unroll
    for (int e=0;e<8;e++){
      float res = w0*(float)a[e] + w1*(float)bb[e] + w2*(float)cc[e] + w3*(float)dd[e];
      f16 hh = (f16)res;
      ho[e] = hh; lo[e] = (f16)(res - (float)hh);
    }
    xh[i] = ho; xl[i] = lo;
  }
}

// ---------------- launch ----------------
extern "C" void kernel_launch(void* const* d_in, const int* in_sizes, int n_in,
                              void* d_out, int out_size, void* d_ws, size_t ws_size,
                              hipStream_t stream) {
  const float* queries = (const float*)d_in[0];
  const float* Wqk     = (const float*)d_in[3];
  const float* Wv      = (const float*)d_in[4];
  const float* Wout    = (const float*)d_in[5];
  const float* bout    = (const float*)d_in[6];
  const float* rot     = (const float*)d_in[7];
  float* out = (float*)d_out;

  const size_t SZ_F16  = (size_t)BH*T_SZ*DH*2;        // 16 MB
  const size_t SZ_WT   = (size_t)1536*512*2;          // 1.5 MB
  const size_t SZ_ROT  = (size_t)128*64*2;            // 16 KB
  const size_t SZ_O    = (size_t)BH*NHASH*T_SZ*DH*2;  // 64 MB
  const size_t OFS_X      = 0;
  const size_t OFS_AH     = OFS_X    + 2*SZ_F16;
  const size_t OFS_AL     = OFS_AH   + SZ_F16;
  const size_t OFS_QK16   = OFS_AL   + SZ_F16;
  const size_t OFS_V16    = OFS_QK16 + SZ_F16;
  const size_t OFS_WTH    = OFS_V16  + SZ_F16;
  const size_t OFS_WTL    = OFS_WTH  + SZ_WT;
  const size_t OFS_ROTH   = OFS_WTL  + SZ_WT;
  const size_t OFS_ROTL   = OFS_ROTH + SZ_ROT;
  const size_t OFS_O      = OFS_ROTL + SZ_ROT;
  const size_t OFS_BUCKET = OFS_O    + SZ_O;
  const size_t OFS_HIST   = OFS_BUCKET + (size_t)BH*NHASH*T_SZ*2;
  const size_t OFS_STARTS = OFS_HIST   + (size_t)BH*NBUCK*4;
  const size_t OFS_ST     = OFS_STARTS + (size_t)BH*NBUCK*4;
  const size_t OFS_LSE    = OFS_ST     + (size_t)BH*TOT*4;
  const size_t OFS_AMB    = OFS_LSE    + (size_t)BH*NHASH*T_SZ*4;
  const size_t OFS_CNT    = OFS_AMB    + (size_t)BH*NHASH*T_SZ*4;
  const size_t WS_NEEDED  = OFS_CNT    + 256;
  if (ws_size < WS_NEEDED) return;

  char* ws = (char*)d_ws;
  f16*      qkl    = (f16*)(ws + OFS_X);               // alias with Xh (disjoint lifetime)
  f16*      Xh     = (f16*)(ws + OFS_X);
  f16*      Xl     = (f16*)(ws + OFS_X + SZ_F16);
  f16*      Ah     = (f16*)(ws + OFS_AH);
  f16*      Al     = (f16*)(ws + OFS_AL);
  f16*      qk16   = (f16*)(ws + OFS_QK16);
  f16*      v16    = (f16*)(ws + OFS_V16);
  f16*      Wth    = (f16*)(ws + OFS_WTH);
  f16*      Wtl    = (f16*)(ws + OFS_WTL);
  f16*      rotTh  = (f16*)(ws + OFS_ROTH);
  f16*      rotTl  = (f16*)(ws + OFS_ROTL);
  f16*      o_f16  = (f16*)(ws + OFS_O);
  unsigned short* bucket = (unsigned short*)(ws + OFS_BUCKET);
  int*      starts = (int*)(ws + OFS_STARTS);
  int*      st     = (int*)(ws + OFS_ST);
  float*    lse    = (float*)(ws + OFS_LSE);
  int*      amb    = (int*)(ws + OFS_AMB);
  int*      cnt    = (int*)(ws + OFS_CNT);

  k0_zero   <<<1, 64, 0, stream>>>(cnt);
  kw_t      <<<(1536*512)/256, 256, 0, stream>>>(Wqk, Wv, Wout, Wth, Wtl);
  kr_t      <<<(128*64)/256, 256, 0, stream>>>(rot, rotTh, rotTl);
  k1a_split <<<(M_TOK*DMODEL/8)/256, 256, 0, stream>>>(queries, Ah, Al);
  g_qkv     <<<dim3(M_TOK/128, 8), 256, 0, stream>>>(Ah, Al, Wth, Wtl, qk16, qkl, v16);
  k2_mfma   <<<(BH*T_SZ)/64, 256, 0, stream>>>(qk16, qkl, rotTh, rotTl, bucket, amb, cnt);
  k2_fix    <<<2048, 64, 0, stream>>>(queries, Wqk, rot, amb, cnt, bucket);
  k3_scan   <<<BH, 256, 0, stream>>>(bucket, starts);
  k3b_scatter<<<BH*NBUCK, 64, 0, stream>>>(bucket, starts, st);
  k4_attn   <<<BH*256, 256, 0, stream>>>(qk16, v16, st, lse, o_f16);
  k5_comb   <<<(BH*T_SZ)/256, 256, 0, stream>>>(lse, o_f16, Xh, Xl);
  g_out     <<<dim3(M_TOK/128, 4), 256, 0, stream>>>(Xh, Xl, Wth, Wtl, bout, out);
}

// Round 3
// 451.439 us; speedup vs baseline: 1.1833x; 1.0887x over previous
//
#include <hip/hip_runtime.h>

typedef unsigned int uint32;
typedef _Float16 f16;
typedef _Float16 f16x8 __attribute__((ext_vector_type(8)));
typedef float f32x4 __attribute__((ext_vector_type(4)));
typedef unsigned short u16x8 __attribute__((ext_vector_type(8)));

#define B_SZ 4
#define T_SZ 4096
#define DMODEL 512
#define NHEAD 8
#define DH 64
#define NHASH 4
#define BH (B_SZ*NHEAD)      // 32
#define NBUCK 256
#define TOT (NHASH*T_SZ)     // 16384
#define M_TOK (B_SZ*T_SZ)    // 16384

#define KSTRIDE 72           // f16 elems per LDS row (128B data + 16B pad)
#define PSTRIDE 136

// split-f16 MFMA hash-score worst-case error ~4e-5*rms; keep >=35x margin.
#define AMB_TAU 1.5e-3f

// ---------------- K0: zero ambiguity counter ----------------
__global__ void k0_zero(int* amb_cnt){
  if (threadIdx.x == 0 && blockIdx.x == 0) *amb_cnt = 0;
}

// ---------------- KW: transpose + split W matrices into Wt[n][k] f16 hi/lo ----
__global__ __launch_bounds__(256) void kw_t(const float* __restrict__ Wqk,
    const float* __restrict__ Wv, const float* __restrict__ Wout,
    f16* __restrict__ Wth, f16* __restrict__ Wtl)
{
  int gid = blockIdx.x*256 + threadIdx.x;   // [0, 1536*512)
  int n = gid >> 9, k = gid & 511;
  int sel = n >> 9, col = n & 511;
  const float* src = (sel==0)? Wqk : (sel==1)? Wv : Wout;
  float v = src[(size_t)k*512 + col];
  f16 h = (f16)v;
  Wth[gid] = h;
  Wtl[gid] = (f16)(v - (float)h);
}

// ---------------- KR: transpose + split rotations into rotT[n=h*32+j][k=dd] --
__global__ __launch_bounds__(256) void kr_t(const float* __restrict__ rot,
    f16* __restrict__ rotTh, f16* __restrict__ rotTl)
{
  int gid = blockIdx.x*256 + threadIdx.x;   // [0, 128*64)
  int n = gid >> 6, dd = gid & 63;
  float v = rot[dd*128 + n];
  f16 h = (f16)v;
  rotTh[gid] = h;
  rotTl[gid] = (f16)(v - (float)h);
}

// ---------------- K1a: split queries (f32) -> A_hi/A_lo (f16) ----------------
__global__ __launch_bounds__(256) void k1a_split(const float* __restrict__ qin,
    f16* __restrict__ Ah, f16* __restrict__ Al)
{
  size_t gid = (size_t)blockIdx.x*256 + threadIdx.x;   // handles 8 floats
  const float4* src = (const float4*)(qin) + gid*2;
  float4 x0 = src[0], x1 = src[1];
  float v[8] = {x0.x,x0.y,x0.z,x0.w, x1.x,x1.y,x1.z,x1.w};
  f16x8 h, l;
  #pragma unroll
  for (int e=0;e<8;e++){ f16 hh=(f16)v[e]; h[e]=hh; l[e]=(f16)(v[e]-(float)hh); }
  ((f16x8*)Ah)[gid] = h;
  ((f16x8*)Al)[gid] = l;
}

// ---------------- G1: split-f16 MFMA GEMM  qk|v = queries @ [Wqk|Wv] ---------
__global__ __launch_bounds__(256) void g_qkv(const f16* __restrict__ Ah,
    const f16* __restrict__ Al, const f16* __restrict__ Wth, const f16* __restrict__ Wtl,
    f16* __restrict__ qk16, f16* __restrict__ qkl, f16* __restrict__ v16)
{
  __shared__ f16 ah[128*KSTRIDE], al[128*KSTRIDE], bh[128*KSTRIDE], bl[128*KSTRIDE];
  int tid = threadIdx.x;
  int m0 = blockIdx.x*128, n0 = blockIdx.y*128;
  int w = tid >> 6, lane = tid & 63;
  int wm = w >> 1, wn = w & 1;
  int c_lane = lane & 15, quad = lane >> 4;

  f32x4 acc[4][4];
  #pragma unroll
  for (int mi=0;mi<4;mi++)
    #pragma unroll
    for (int ni=0;ni<4;ni++) acc[mi][ni] = (f32x4){0.f,0.f,0.f,0.f};

  int sr = tid >> 1, sc = (tid & 1) * 32;
  for (int kc=0; kc<8; kc++){
    int k0 = kc*64;
    {
      const f16x8* pah = (const f16x8*)(Ah + (size_t)(m0+sr)*512 + k0 + sc);
      const f16x8* pal = (const f16x8*)(Al + (size_t)(m0+sr)*512 + k0 + sc);
      const f16x8* pbh = (const f16x8*)(Wth + (size_t)(n0+sr)*512 + k0 + sc);
      const f16x8* pbl = (const f16x8*)(Wtl + (size_t)(n0+sr)*512 + k0 + sc);
      f16x8* dah = (f16x8*)&ah[sr*KSTRIDE + sc];
      f16x8* dal = (f16x8*)&al[sr*KSTRIDE + sc];
      f16x8* dbh = (f16x8*)&bh[sr*KSTRIDE + sc];
      f16x8* dbl = (f16x8*)&bl[sr*KSTRIDE + sc];
      #pragma unroll
      for (int i=0;i<4;i++){ dah[i]=pah[i]; dal[i]=pal[i]; dbh[i]=pbh[i]; dbl[i]=pbl[i]; }
    }
    __syncthreads();
    f16x8 fah[4][2], fal[4][2], fbh[4][2], fbl[4][2];
    #pragma unroll
    for (int i=0;i<4;i++)
      #pragma unroll
      for (int kb=0;kb<2;kb++){
        int ma = (wm*64 + i*16 + c_lane)*KSTRIDE + kb*32 + quad*8;
        int nb = (wn*64 + i*16 + c_lane)*KSTRIDE + kb*32 + quad*8;
        fah[i][kb] = *(const f16x8*)&ah[ma];
        fal[i][kb] = *(const f16x8*)&al[ma];
        fbh[i][kb] = *(const f16x8*)&bh[nb];
        fbl[i][kb] = *(const f16x8*)&bl[nb];
      }
    #pragma unroll
    for (int kb=0;kb<2;kb++)
      #pragma unroll
      for (int p=0;p<3;p++)
        #pragma unroll
        for (int mi=0;mi<4;mi++)
          #pragma unroll
          for (int ni=0;ni<4;ni++){
            f16x8 a = (p==2)? fal[mi][kb] : fah[mi][kb];
            f16x8 b = (p==1)? fbl[ni][kb] : fbh[ni][kb];
            acc[mi][ni] = __builtin_amdgcn_mfma_f32_16x16x32_f16(a, b, acc[mi][ni], 0,0,0);
          }
    __syncthreads();
  }

  // epilogue: n<512 -> qk16(hi)+qkl(lo); n>=512 -> v16
  #pragma unroll
  for (int mi=0;mi<4;mi++)
    #pragma unroll
    for (int ni=0;ni<4;ni++)
      #pragma unroll
      for (int r=0;r<4;r++){
        int n = n0 + wn*64 + ni*16 + c_lane;
        int tok = m0 + wm*64 + mi*16 + quad*4 + r;
        float val = acc[mi][ni][r];
        int b = tok >> 12, tp = tok & 4095;
        if (n < 512){
          int head = n >> 6, dd = n & 63;
          size_t idx = ((size_t)(b*NHEAD+head)*T_SZ + tp)*DH + dd;
          f16 hv = (f16)val;
          qk16[idx] = hv;
          qkl[idx]  = (f16)(val - (float)hv);
        } else {
          int j = n - 512, head = j >> 6, dd = j & 63;
          size_t idx = ((size_t)(b*NHEAD+head)*T_SZ + tp)*DH + dd;
          v16[idx] = (f16)val;
        }
      }
}

// ---------------- G2: fused round-combine + split-f16 GEMM  out = X @ Wout ----
// v2: k5_comb is FUSED into the A-tile staging (k5 was 79us, 3x read-amplified,
// 2x write-amplified: 260MB HBM for 98MB ideal). kc == head index, so the
// A-slice X[tok][kc*64+sc..] = sum_r w_r * o_f16[((b*8+kc)*4+r)*T + t][sc..].
// Identical float-op order as k5 (w0*a + w1*b + w2*c + w3*d, then hi/lo split)
// -> bit-identical GEMM inputs. Saves 32MB X write + 32MB X read at HBM.
__global__ __launch_bounds__(256) void g_out(const float* __restrict__ lse,
    const f16* __restrict__ o_f16, const f16* __restrict__ Wth, const f16* __restrict__ Wtl,
    const float* __restrict__ bout, float* __restrict__ out)
{
  __shared__ f16 ah[128*KSTRIDE], al[128*KSTRIDE], bh[128*KSTRIDE], bl[128*KSTRIDE];
  int tid = threadIdx.x;
  int m0 = blockIdx.x*128, n0 = blockIdx.y*128;
  int w = tid >> 6, lane = tid & 63;
  int wm = w >> 1, wn = w & 1;
  int c_lane = lane & 15, quad = lane >> 4;
  const f16* Bh_base = Wth + (size_t)1024*512;   // Wout section
  const f16* Bl_base = Wtl + (size_t)1024*512;

  f32x4 acc[4][4];
  #pragma unroll
  for (int mi=0;mi<4;mi++)
    #pragma unroll
    for (int ni=0;ni<4;ni++) acc[mi][ni] = (f32x4){0.f,0.f,0.f,0.f};

  int sr = tid >> 1, sc = (tid & 1) * 32;
  int tok = m0 + sr;
  int tb = tok >> 12, tt = tok & 4095;

  for (int kc=0; kc<8; kc++){
    int k0 = kc*64;
    {
      // ---- fused k5: combine 4 hash rounds for head kc, rows tok ----
      size_t lbase = ((size_t)(tb*NHEAD + kc)*NHASH)*T_SZ + tt;
      float l0 = lse[lbase];
      float l1 = lse[lbase + T_SZ];
      float l2 = lse[lbase + 2*T_SZ];
      float l3 = lse[lbase + 3*T_SZ];
      float M = fmaxf(fmaxf(l0,l1), fmaxf(l2,l3));
      float e0 = __expf(l0-M), e1 = __expf(l1-M), e2 = __expf(l2-M), e3 = __expf(l3-M);
      float inv = 1.0f/(e0+e1+e2+e3);
      float w0=e0*inv, w1=e1*inv, w2=e2*inv, w3=e3*inv;
      const f16x8* r0 = (const f16x8*)(o_f16 + lbase*DH + sc);
      const f16x8* r1 = (const f16x8*)(o_f16 + (lbase + (size_t)T_SZ)*DH + sc);
      const f16x8* r2 = (const f16x8*)(o_f16 + (lbase + (size_t)2*T_SZ)*DH + sc);
      const f16x8* r3 = (const f16x8*)(o_f16 + (lbase + (size_t)3*T_SZ)*DH + sc);
      const f16x8* pbh = (const f16x8*)(Bh_base + (size_t)(n0+sr)*512 + k0 + sc);
      const f16x8* pbl = (const f16x8*)(Bl_base + (size_t)(n0+sr)*512 + k0 + sc);
      f16x8* dah = (f16x8*)&ah[sr*KSTRIDE + sc];
      f16x8* dal = (f16x8*)&al[sr*KSTRIDE + sc];
      f16x8* dbh = (f16x8*)&bh[sr*KSTRIDE + sc];
      f16x8* dbl = (f16x8*)&bl[sr*KSTRIDE + sc];
      #pragma unroll
      for (int i=0;i<4;i++){
        f16x8 a = r0[i], bb = r1[i], cc = r2[i], dd = r3[i];
        f16x8 ho, lo;
        #pragma unroll
        for (int e=0;e<8;e++){
          float res = w0*(float)a[e] + w1*(float)bb[e] + w2*(float)cc[e] + w3*(float)dd[e];
          f16 hh = (f16)res;
          ho[e] = hh; lo[e] = (f16)(res - (float)hh);
        }
        dah[i] = ho; dal[i] = lo;
        dbh[i] = pbh[i]; dbl[i] = pbl[i];
      }
    }
    __syncthreads();
    f16x8 fah[4][2], fal[4][2], fbh[4][2], fbl[4][2];
    #pragma unroll
    for (int i=0;i<4;i++)
      #pragma unroll
      for (int kb=0;kb<2;kb++){
        int ma = (wm*64 + i*16 + c_lane)*KSTRIDE + kb*32 + quad*8;
        int nb = (wn*64 + i*16 + c_lane)*KSTRIDE + kb*32 + quad*8;
        fah[i][kb] = *(const f16x8*)&ah[ma];
        fal[i][kb] = *(const f16x8*)&al[ma];
        fbh[i][kb] = *(const f16x8*)&bh[nb];
        fbl[i][kb] = *(const f16x8*)&bl[nb];
      }
    #pragma unroll
    for (int kb=0;kb<2;kb++)
      #pragma unroll
      for (int p=0;p<3;p++)
        #pragma unroll
        for (int mi=0;mi<4;mi++)
          #pragma unroll
          for (int ni=0;ni<4;ni++){
            f16x8 a = (p==2)? fal[mi][kb] : fah[mi][kb];
            f16x8 b = (p==1)? fbl[ni][kb] : fbh[ni][kb];
            acc[mi][ni] = __builtin_amdgcn_mfma_f32_16x16x32_f16(a, b, acc[mi][ni], 0,0,0);
          }
    __syncthreads();
  }

  #pragma unroll
  for (int mi=0;mi<4;mi++)
    #pragma unroll
    for (int ni=0;ni<4;ni++){
      int n = n0 + wn*64 + ni*16 + c_lane;
      float bn = bout[n];
      #pragma unroll
      for (int r=0;r<4;r++){
        int tk2 = m0 + wm*64 + mi*16 + quad*4 + r;
        out[(size_t)tk2*512 + n] = acc[mi][ni][r] + bn;
      }
    }
}

// ---------------- K2: LSH hashing, rot-as-A MFMA + in-lane argmax epilogue ----
__global__ __launch_bounds__(256, 4) void k2_mfma(const f16* __restrict__ qkh,
    const f16* __restrict__ qkl, const f16* __restrict__ rotTh, const f16* __restrict__ rotTl,
    unsigned short* __restrict__ bucket,
    int* __restrict__ amb_list, int* __restrict__ amb_cnt)
{
  int tid = threadIdx.x;
  int w = tid >> 6, lane = tid & 63;
  int c_lane = lane & 15, quad = lane >> 4;
  int tok0 = (blockIdx.x*4 + w)*16;            // 16 tokens per wave
  size_t rowb = (size_t)(tok0 + c_lane)*64;

  // B fragments: token hi/lo (col = token = c_lane, k = kb*32 + quad*8 + e)
  f16x8 tbh[2], tbl[2];
  #pragma unroll
  for (int kb=0;kb<2;kb++){
    tbh[kb] = *(const f16x8*)&qkh[rowb + kb*32 + quad*8];
    tbl[kb] = *(const f16x8*)&qkl[rowb + kb*32 + quad*8];
  }

  f32x4 acc[8];
  #pragma unroll
  for (int mi=0;mi<8;mi++) acc[mi] = (f32x4){0.f,0.f,0.f,0.f};

  // A fragments: rot rows j = mi*16 + c_lane (L1-resident, 32KB total)
  #pragma unroll
  for (int mi=0;mi<8;mi++){
    int aoff = (mi*16 + c_lane)*64;
    #pragma unroll
    for (int kb=0;kb<2;kb++){
      f16x8 arh = *(const f16x8*)&rotTh[aoff + kb*32 + quad*8];
      f16x8 arl = *(const f16x8*)&rotTl[aoff + kb*32 + quad*8];
      acc[mi] = __builtin_amdgcn_mfma_f32_16x16x32_f16(arh, tbh[kb], acc[mi], 0,0,0);
      acc[mi] = __builtin_amdgcn_mfma_f32_16x16x32_f16(arl, tbh[kb], acc[mi], 0,0,0);
      acc[mi] = __builtin_amdgcn_mfma_f32_16x16x32_f16(arh, tbl[kb], acc[mi], 0,0,0);
    }
  }

  // lane (c_lane, quad) holds scores s[j] for token tok0+c_lane,
  // j = mi*16 + quad*4 + r  (mi = 0..7, r = 0..3)
  int tokg = tok0 + c_lane;
  int bhh = tokg >> 12, t = tokg & 4095;

  #pragma unroll
  for (int h=0; h<4; h++){
    float m1 = -1e30f, m2 = -1e30f, ssq = 0.f; int b1 = 0;
    #pragma unroll
    for (int u=0; u<8; u++){
      float v = acc[2*h + (u>>2)][u&3];
      int bidd = (u>>2)*16 + quad*4 + (u&3);   // within-hash index [0,32)
      ssq += v*v;
      if (v > m1){ m2=m1; m1=v; b1=bidd; } else if (v > m2) m2=v;
      float nv = -v;
      if (nv > m1){ m2=m1; m1=nv; b1=bidd+32; } else if (nv > m2) m2=nv;
    }
    // cross-quad reduce (lane bits 4,5)
    #pragma unroll
    for (int d2=16; d2<64; d2<<=1){
      float om1 = __shfl_xor(m1, d2);
      float om2 = __shfl_xor(m2, d2);
      int   ob1 = __shfl_xor(b1, d2);
      ssq += __shfl_xor(ssq, d2);
      if (om1 > m1){ m2 = fmaxf(m1, om2); m1 = om1; b1 = ob1; }
      else          { m2 = fmaxf(m2, om1); }
    }
    if (quad == 0){
      float rms = sqrtf(ssq * (1.0f/32.0f));
      if (m1 - m2 < AMB_TAU * rms){
        int idx = atomicAdd(amb_cnt, 1);
        amb_list[idx] = (bhh<<14) | (h<<12) | t;
      } else {
        bucket[((bhh*NHASH + h)<<12) + t] = (unsigned short)(b1 + (h<<6));
      }
    }
  }
}

// ---------------- K2fix: exact f64 recompute for ambiguous decisions ----------
__global__ __launch_bounds__(64) void k2_fix(const float* __restrict__ qin,
    const float* __restrict__ Wqk, const float* __restrict__ rot,
    const int* __restrict__ amb_list, const int* __restrict__ amb_cnt,
    unsigned short* __restrict__ bucket)
{
  __shared__ __align__(16) float qs[512];
  __shared__ double qk64[64];
  __shared__ double accs[32];
  int n = *amb_cnt;
  int lane = threadIdx.x;
  for (int it = blockIdx.x; it < n; it += gridDim.x){
    int gid = amb_list[it];
    int t = gid & (T_SZ-1);
    int h = (gid >> 12) & 3;
    int bh = gid >> 14;
    int b = bh >> 3, head = bh & 7;
    const float4* qrow4 = (const float4*)(qin + ((size_t)b*T_SZ + t)*DMODEL);
    float4 x0 = qrow4[lane];
    float4 x1 = qrow4[lane + 64];
    *(float4*)&qs[lane*4]       = x0;
    *(float4*)&qs[256 + lane*4] = x1;
    __syncthreads();
    const float* wcol = Wqk + head*64 + lane;
    double s = 0.0;
    #pragma unroll 16
    for (int d=0; d<512; d++)
      s += (double)qs[d] * (double)wcol[(size_t)d*512];
    qk64[lane] = s;
    __syncthreads();
    if (lane < 32){
      double a = 0.0;
      #pragma unroll 16
      for (int f=0; f<64; f++)
        a += qk64[f] * (double)rot[f*(NHASH*32) + h*32 + lane];
      accs[lane] = a;
    }
    __syncthreads();
    if (lane == 0){
      double best = accs[0]; int bk = 0;
      for (int k=1;k<64;k++){
        double vv = (k<32)? accs[k] : -accs[k-32];
        if (vv > best){ best = vv; bk = k; }
      }
      int g = bk + (h<<6);
      bucket[((bh*NHASH + h)<<12) + t] = (unsigned short)g;
    }
    __syncthreads();
  }
}

// ---------------- K3: LDS histogram from bucket + exclusive prefix scan -------
__global__ __launch_bounds__(256) void k3_scan(const unsigned short* __restrict__ bucket,
    int* __restrict__ starts){
  __shared__ int s[256];
  int bh = blockIdx.x, tid = threadIdx.x;
  s[tid] = 0;
  __syncthreads();
  const u16x8* b8 = (const u16x8*)(bucket + ((size_t)bh*NHASH << 12));
  for (int i = tid; i < 2048; i += 256){   // 16384 u16 = 2048 x u16x8
    u16x8 x = b8[i];
    #pragma unroll
    for (int e=0;e<8;e++) atomicAdd(&s[x[e]], 1);
  }
  __syncthreads();
  int v = s[tid];
  __syncthreads();
  for (int off=1; off<256; off<<=1){
    int a = (tid >= off) ? s[tid-off] : 0;
    __syncthreads();
    s[tid] += a;
    __syncthreads();
  }
  starts[bh*256 + tid] = s[tid] - v;
}

// ---------------- K3b: stable counting-sort scatter ----------------
__global__ __launch_bounds__(64) void k3b_scatter(const unsigned short* __restrict__ bucket,
    const int* __restrict__ starts, int* __restrict__ st)
{
  int blk = blockIdx.x;
  int bh = blk >> 8; int g = blk & 255; int h = g >> 6;
  int lane = threadIdx.x;
  const unsigned short* brow = bucket + ((bh*NHASH + h)<<12);
  int base = starts[bh*NBUCK + g];
  for (int step=0; step<64; step++){
    int t = step*64 + lane;
    bool pred = (brow[t] == (unsigned short)g);
    unsigned long long mask = __ballot(pred);
    if (pred){
      int off = __popcll(mask & ((1ull<<lane) - 1ull));
      st[bh*TOT + base + off] = t;
    }
    base += __popcll(mask);
  }
}

// ---------------- K4: MFMA chunked LSH attention ------------------------------
// 4 cooperative waves per chunk (wave w owns query sub-tile mi=w).
// 36864B LDS -> 4 blocks/CU at 256 thr = 16 waves/CU. XCD-aware swizzle.
__global__ __launch_bounds__(256, 4) void k4_attn(const f16* __restrict__ qk16,
    const f16* __restrict__ v16, const int* __restrict__ st,
    float* __restrict__ lse_out, f16* __restrict__ o_out)
{
  __shared__ __align__(16) char smem[36864];
  f16*   k_lds   = (f16*)smem;                 // 128 x KSTRIDE (alias p_lds)
  f16*   p_lds   = (f16*)smem;                 // 64 x PSTRIDE
  f16*   vT      = (f16*)(smem + 18432);       // 64 x PSTRIDE (d-major)
  float* invnorm = (float*)(smem + 35840);
  int*   kv_t    = (int*)(smem + 36352);

  int bid = blockIdx.x;
  int swz = (bid & 7) * 1024 + (bid >> 3);     // bijective: 8192 = 8*1024
  int bh = swz >> 8; int c = swz & 255;
  int h = c >> 6; int cp = (c + 255) & 255;
  int tid = threadIdx.x;
  int w = tid >> 6, lane = tid & 63;
  int c_lane = lane & 15, quad = lane >> 4;
  const int* strow = st + bh*TOT;

  // ---- load phase: threads 0..127, one full K/V row each
  if (tid < 128){
    int row = tid;
    int slot = (row < 64) ? (c*64 + row) : (cp*64 + row - 64);
    int t = strow[slot];
    kv_t[row] = t;
    const f16x8* kr = (const f16x8*)(qk16 + ((size_t)bh*T_SZ + t)*DH);
    const f16x8* vr = (const f16x8*)(v16  + ((size_t)bh*T_SZ + t)*DH);
    f16x8 kv[8], vv[8];
    float ss = 0.f;
    #pragma unroll
    for (int i=0;i<8;i++){
      f16x8 x = kr[i]; kv[i] = x;
      vv[i] = vr[i];
      #pragma unroll
      for (int e=0;e<8;e++){ float f = (float)x[e]; ss += f*f; }
    }
    invnorm[row] = 1.0f / fmaxf(sqrtf(ss), 1e-12f);
    f16x8* kd = (f16x8*)&k_lds[row*KSTRIDE];
    #pragma unroll
    for (int i=0;i<8;i++) kd[i] = kv[i];
    #pragma unroll
    for (int i=0;i<8;i++){
      #pragma unroll
      for (int e=0;e<8;e++) vT[(i*8+e)*PSTRIDE + row] = vv[i][e];
    }
  }
  __syncthreads();

  // ---- QK^T: wave w computes query sub-tile mi = w ----
  int mi = w;
  f16x8 aq[2];
  #pragma unroll
  for (int kb=0;kb<2;kb++)
    aq[kb] = *(const f16x8*)&k_lds[(mi*16 + c_lane)*KSTRIDE + kb*32 + quad*8];

  f32x4 accS[8];
  #pragma unroll
  for (int ni=0;ni<8;ni++) accS[ni] = (f32x4){0.f,0.f,0.f,0.f};

  #pragma unroll
  for (int ni=0;ni<8;ni++){
    int rowb = ni*16 + c_lane;
    f16 sc = (f16)invnorm[rowb];
    f16x8 b0 = *(const f16x8*)&k_lds[rowb*KSTRIDE + 0*32 + quad*8];
    f16x8 b1 = *(const f16x8*)&k_lds[rowb*KSTRIDE + 1*32 + quad*8];
    b0 *= sc; b1 *= sc;
    accS[ni] = __builtin_amdgcn_mfma_f32_16x16x32_f16(aq[0], b0, accS[ni], 0,0,0);
    accS[ni] = __builtin_amdgcn_mfma_f32_16x16x32_f16(aq[1], b1, accS[ni], 0,0,0);
  }

  int tq[4];
  #pragma unroll
  for (int r=0;r<4;r++) tq[r] = kv_t[mi*16 + quad*4 + r];
  int tk[8];
  #pragma unroll
  for (int ni=0;ni<8;ni++) tk[ni] = kv_t[ni*16 + c_lane];

  float mrow[4], lrow[4];
  #pragma unroll
  for (int r=0;r<4;r++){
    float mx = -1e30f;
    #pragma unroll
    for (int ni=0;ni<8;ni++){
      float s = accS[ni][r] * 0.125f;
      if (tk[ni] == tq[r]) s = -50000.0f;
      accS[ni][r] = s;
      mx = fmaxf(mx, s);
    }
    mx = fmaxf(mx, __shfl_xor(mx, 1));
    mx = fmaxf(mx, __shfl_xor(mx, 2));
    mx = fmaxf(mx, __shfl_xor(mx, 4));
    mx = fmaxf(mx, __shfl_xor(mx, 8));
    mrow[r] = mx;
    float ls = 0.f;
    #pragma unroll
    for (int ni=0;ni<8;ni++){
      float e = __expf(accS[ni][r] - mx);
      accS[ni][r] = e;
      ls += e;
    }
    ls += __shfl_xor(ls, 1);
    ls += __shfl_xor(ls, 2);
    ls += __shfl_xor(ls, 4);
    ls += __shfl_xor(ls, 8);
    lrow[r] = ls;
  }

  // all waves done reading k_lds (aliased with p_lds) before any P write
  __syncthreads();

  #pragma unroll
  for (int ni=0;ni<8;ni++)
    #pragma unroll
    for (int r=0;r<4;r++)
      p_lds[(mi*16 + quad*4 + r)*PSTRIDE + ni*16 + c_lane] = (f16)accS[ni][r];

  // wave reads only its own P rows -> no cross-wave barrier needed
  f16x8 pa[4];
  #pragma unroll
  for (int kb=0;kb<4;kb++)
    pa[kb] = *(const f16x8*)&p_lds[(mi*16 + c_lane)*PSTRIDE + kb*32 + quad*8];

  size_t rowbase = (size_t)(bh*NHASH + h)*T_SZ;
  #pragma unroll
  for (int ni2=0;ni2<4;ni2++){
    f16x8 bv[4];
    #pragma unroll
    for (int kb=0;kb<4;kb++)
      bv[kb] = *(const f16x8*)&vT[(ni2*16 + c_lane)*PSTRIDE + kb*32 + quad*8];
    f32x4 accO = (f32x4){0.f,0.f,0.f,0.f};
    #pragma unroll
    for (int kb=0;kb<4;kb++)
      accO = __builtin_amdgcn_mfma_f32_16x16x32_f16(pa[kb], bv[kb], accO, 0,0,0);
    #pragma unroll
    for (int r=0;r<4;r++){
      float invl = 1.0f / lrow[r];
      f16* orow = o_out + (rowbase + tq[r])*DH;
      orow[ni2*16 + c_lane] = (f16)(accO[r] * invl);
    }
  }
  #pragma unroll
  for (int r=0;r<4;r++){
    if (c_lane == 0)
      lse_out[rowbase + tq[r]] = mrow[r] + logf(lrow[r]);
  }
}

// ---------------- launch ----------------
extern "C" void kernel_launch(void* const* d_in, const int* in_sizes, int n_in,
                              void* d_out, int out_size, void* d_ws, size_t ws_size,
                              hipStream_t stream) {
  const float* queries = (const float*)d_in[0];
  const float* Wqk     = (const float*)d_in[3];
  const float* Wv      = (const float*)d_in[4];
  const float* Wout    = (const float*)d_in[5];
  const float* bout    = (const float*)d_in[6];
  const float* rot     = (const float*)d_in[7];
  float* out = (float*)d_out;

  const size_t SZ_F16  = (size_t)BH*T_SZ*DH*2;        // 16 MB
  const size_t SZ_WT   = (size_t)1536*512*2;          // 1.5 MB
  const size_t SZ_ROT  = (size_t)128*64*2;            // 16 KB
  const size_t SZ_O    = (size_t)BH*NHASH*T_SZ*DH*2;  // 64 MB
  const size_t OFS_X      = 0;
  const size_t OFS_AH     = OFS_X    + 2*SZ_F16;
  const size_t OFS_AL     = OFS_AH   + SZ_F16;
  const size_t OFS_QK16   = OFS_AL   + SZ_F16;
  const size_t OFS_V16    = OFS_QK16 + SZ_F16;
  const size_t OFS_WTH    = OFS_V16  + SZ_F16;
  const size_t OFS_WTL    = OFS_WTH  + SZ_WT;
  const size_t OFS_ROTH   = OFS_WTL  + SZ_WT;
  const size_t OFS_ROTL   = OFS_ROTH + SZ_ROT;
  const size_t OFS_O      = OFS_ROTL + SZ_ROT;
  const size_t OFS_BUCKET = OFS_O    + SZ_O;
  const size_t OFS_HIST   = OFS_BUCKET + (size_t)BH*NHASH*T_SZ*2;
  const size_t OFS_STARTS = OFS_HIST   + (size_t)BH*NBUCK*4;
  const size_t OFS_ST     = OFS_STARTS + (size_t)BH*NBUCK*4;
  const size_t OFS_LSE    = OFS_ST     + (size_t)BH*TOT*4;
  const size_t OFS_AMB    = OFS_LSE    + (size_t)BH*NHASH*T_SZ*4;
  const size_t OFS_CNT    = OFS_AMB    + (size_t)BH*NHASH*T_SZ*4;
  const size_t WS_NEEDED  = OFS_CNT    + 256;
  if (ws_size < WS_NEEDED) return;

  char* ws = (char*)d_ws;
  f16*      qkl    = (f16*)(ws + OFS_X);               // lo split of qk (g_qkv/k2)
  f16*      Ah     = (f16*)(ws + OFS_AH);
  f16*      Al     = (f16*)(ws + OFS_AL);
  f16*      qk16   = (f16*)(ws + OFS_QK16);
  f16*      v16    = (f16*)(ws + OFS_V16);
  f16*      Wth    = (f16*)(ws + OFS_WTH);
  f16*      Wtl    = (f16*)(ws + OFS_WTL);
  f16*      rotTh  = (f16*)(ws + OFS_ROTH);
  f16*      rotTl  = (f16*)(ws + OFS_ROTL);
  f16*      o_f16  = (f16*)(ws + OFS_O);
  unsigned short* bucket = (unsigned short*)(ws + OFS_BUCKET);
  int*      starts = (int*)(ws + OFS_STARTS);
  int*      st     = (int*)(ws + OFS_ST);
  float*    lse    = (float*)(ws + OFS_LSE);
  int*      amb    = (int*)(ws + OFS_AMB);
  int*      cnt    = (int*)(ws + OFS_CNT);

  k0_zero   <<<1, 64, 0, stream>>>(cnt);
  kw_t      <<<(1536*512)/256, 256, 0, stream>>>(Wqk, Wv, Wout, Wth, Wtl);
  kr_t      <<<(128*64)/256, 256, 0, stream>>>(rot, rotTh, rotTl);
  k1a_split <<<(M_TOK*DMODEL/8)/256, 256, 0, stream>>>(queries, Ah, Al);
  g_qkv     <<<dim3(M_TOK/128, 8), 256, 0, stream>>>(Ah, Al, Wth, Wtl, qk16, qkl, v16);
  k2_mfma   <<<(BH*T_SZ)/64, 256, 0, stream>>>(qk16, qkl, rotTh, rotTl, bucket, amb, cnt);
  k2_fix    <<<2048, 64, 0, stream>>>(queries, Wqk, rot, amb, cnt, bucket);
  k3_scan   <<<BH, 256, 0, stream>>>(bucket, starts);
  k3b_scatter<<<BH*NBUCK, 64, 0, stream>>>(bucket, starts, st);
  k4_attn   <<<BH*256, 256, 0, stream>>>(qk16, v16, st, lse, o_f16);
  g_out     <<<dim3(M_TOK/128, 4), 256, 0, stream>>>(lse, o_f16, Wth, Wtl, bout, out);
}